// Round 3
// baseline (863.482 us; speedup 1.0000x reference)
//
#include <hip/hip_runtime.h>
#include <math.h>

static constexpr int BATCH = 64;
static constexpr int SEQ   = 32;
static constexpr int TOK   = BATCH * SEQ;   // 2048
static constexpr int DIM   = 1024;
static constexpr int NH    = 16;
static constexpr int HDIM  = 64;
static constexpr int FFD   = 2048;
static constexpr int LAYERS= 4;
static constexpr int NHEAD_OUT = 26;
static constexpr int IDH   = 512;

typedef __bf16 bf16_t;
typedef __bf16 bf16x8 __attribute__((ext_vector_type(8)));
typedef float  f32x4  __attribute__((ext_vector_type(4)));
typedef unsigned short us4 __attribute__((ext_vector_type(4)));

__device__ __forceinline__ unsigned short f2bfu(float f) {
    return __builtin_bit_cast(unsigned short, (bf16_t)f);
}

__device__ __forceinline__ void gload_lds16(const void* gp, void* lp) {
    __builtin_amdgcn_global_load_lds(
        (const __attribute__((address_space(1))) unsigned int*)gp,
        (__attribute__((address_space(3))) unsigned int*)lp,
        16, 0, 0);
}

// ---------------- block-wide sum (256 threads = 4 waves) ----------------
__device__ __forceinline__ float block_sum(float v, float* red) {
    #pragma unroll
    for (int off = 32; off > 0; off >>= 1) v += __shfl_down(v, off);
    int lane = threadIdx.x & 63;
    int w    = threadIdx.x >> 6;
    if (lane == 0) red[w] = v;
    __syncthreads();
    float t = red[0] + red[1] + red[2] + red[3];
    __syncthreads();
    return t;
}

// ---------------- LayerNorm -> bf16 output
template<bool PRE>
__global__ __launch_bounds__(256) void ln_kernel(const float* __restrict__ x,
                                                 const float* __restrict__ g,
                                                 const float* __restrict__ b,
                                                 bf16_t* __restrict__ y) {
    __shared__ float red[4];
    long row = blockIdx.x;
    const float* xr = x + row * DIM;
    int tid = threadIdx.x;
    float4 v = *(const float4*)(xr + tid * 4);
    if (PRE) {
        float s  = block_sum(v.x + v.y + v.z + v.w, red);
        float mu = s * (1.0f / DIM);
        v.x -= mu; v.y -= mu; v.z -= mu; v.w -= mu;
        float ss = block_sum(v.x*v.x + v.y*v.y + v.z*v.z + v.w*v.w, red);
        float r  = 1.0f / sqrtf(ss * (1.0f / DIM) + 1e-6f);
        v.x *= r; v.y *= r; v.z *= r; v.w *= r;
    }
    float s  = block_sum(v.x + v.y + v.z + v.w, red);
    float mu = s * (1.0f / DIM);
    v.x -= mu; v.y -= mu; v.z -= mu; v.w -= mu;
    float ss = block_sum(v.x*v.x + v.y*v.y + v.z*v.z + v.w*v.w, red);
    float r  = 1.0f / sqrtf(ss * (1.0f / DIM) + 1e-5f);
    float4 gg = *(const float4*)(g + tid * 4);
    float4 bb = *(const float4*)(b + tid * 4);
    us4 o;
    o.x = f2bfu(v.x * r * gg.x + bb.x);
    o.y = f2bfu(v.y * r * gg.y + bb.y);
    o.z = f2bfu(v.z * r * gg.z + bb.z);
    o.w = f2bfu(v.w * r * gg.w + bb.w);
    *(us4*)(y + row * DIM + tid * 4) = o;
}

// ---------------- transpose + fp32->bf16: W[K][N] -> WT[N][K], grouped over z
__global__ __launch_bounds__(256) void transpose_cvt(const float* __restrict__ W,
                                                     bf16_t* __restrict__ WT,
                                                     int K, int N) {
    long g = blockIdx.z;
    W  += g * (long)K * N;
    WT += g * (long)K * N;
    __shared__ float t[32][33];
    int n0 = blockIdx.x * 32, k0 = blockIdx.y * 32;
    int r = threadIdx.x >> 3;          // 0..31
    int c = (threadIdx.x & 7) * 4;     // 0,4,...,28
    float4 v = *(const float4*)(W + (long)(k0 + r) * N + n0 + c);
    t[r][c] = v.x; t[r][c+1] = v.y; t[r][c+2] = v.z; t[r][c+3] = v.w;
    __syncthreads();
    us4 o;
    o.x = f2bfu(t[c+0][r]);
    o.y = f2bfu(t[c+1][r]);
    o.z = f2bfu(t[c+2][r]);
    o.w = f2bfu(t[c+3][r]);
    *(us4*)(WT + (long)(n0 + r) * K + k0 + c) = o;
}

// ---------------- MFMA GEMM: A[M][K] bf16, BT[N][K] bf16, C = A @ B (+epilogue)
// Fragment-ordered LDS staging (conflict-free ds_read_b128) + T3-min dbuf prefetch.
// EPI: 0 = none (bf16 out), 1 = +bias +resid (fp32 out),
//      2 = +bias, gelu (bf16 out), 3 = +bias, relu (bf16 out)
template<int BM, int BN, int WM, int WN, int EPI>
__global__ __launch_bounds__(256) void gemm_bt(
    const bf16_t* __restrict__ A, const bf16_t* __restrict__ BT,
    const float* __restrict__ bias, const float* __restrict__ resid,
    void* __restrict__ Cv,
    int M, int N, int K, long sA, long sB, long sbias, long sC)
{
    constexpr int WAVES_N = BN / WN;
    constexpr int FM = WM / 16, FN = WN / 16;
    constexpr int SA = BM / 16, SB = BN / 16;   // 1KB subtiles per K-step
    long g = blockIdx.z;
    A  += g * sA;
    BT += g * sB;
    if (EPI != 0) bias += g * sbias;
    float*  Cf = (float*)Cv + g * sC;
    bf16_t* Ch = (bf16_t*)Cv + g * sC;

    __shared__ bf16_t As[2][BM * 32];
    __shared__ bf16_t Bs[2][BN * 32];

    int tid  = threadIdx.x;
    int wave = tid >> 6, lane = tid & 63;
    int wr = wave / WAVES_N, wc = wave % WAVES_N;
    int m0 = blockIdx.y * BM, n0 = blockIdx.x * BN;

    f32x4 acc[FM][FN];
    #pragma unroll
    for (int m = 0; m < FM; ++m)
        #pragma unroll
        for (int n = 0; n < FN; ++n)
            acc[m][n] = f32x4{0.f, 0.f, 0.f, 0.f};

    const char* Ab = (const char*)A;
    const char* Bb = (const char*)BT;
    long rsb = (long)K * 2;                 // row byte stride
    int  lr  = lane & 15;                   // fragment row
    int  lkb = (lane >> 4) * 16;            // fragment k-chunk byte offset

    // per-lane global bases (pre-permuted so LDS stays linear in lane order)
    const char* Abase = Ab + (long)(m0 + lr) * rsb + lkb;
    const char* Bbase = Bb + (long)(n0 + lr) * rsb + lkb;

#define STAGE(c, k0) do {                                                   \
    long kb_ = (long)(k0) * 2;                                              \
    _Pragma("unroll")                                                       \
    for (int i_ = 0; i_ < SA / 4; ++i_) {                                   \
        int s_ = i_ * 4 + wave;                                             \
        gload_lds16(Abase + (long)s_ * 16 * rsb + kb_,                      \
                    (char*)&As[c][0] + s_ * 1024);                          \
    }                                                                       \
    _Pragma("unroll")                                                       \
    for (int i_ = 0; i_ < SB / 4; ++i_) {                                   \
        int s_ = i_ * 4 + wave;                                             \
        gload_lds16(Bbase + (long)s_ * 16 * rsb + kb_,                      \
                    (char*)&Bs[c][0] + s_ * 1024);                          \
    }                                                                       \
} while (0)

    int nt = K >> 5;
    STAGE(0, 0);
    __syncthreads();
    int cur = 0;
    for (int t = 0; t < nt; ++t) {
        if (t + 1 < nt) STAGE(cur ^ 1, (t + 1) << 5);
        bf16x8 af[FM], bq[FN];
        #pragma unroll
        for (int m = 0; m < FM; ++m)
            af[m] = *(const bf16x8*)((const char*)&As[cur][0] +
                                     (wr * (WM / 16) + m) * 1024 + (lane << 4));
        #pragma unroll
        for (int n = 0; n < FN; ++n)
            bq[n] = *(const bf16x8*)((const char*)&Bs[cur][0] +
                                     (wc * (WN / 16) + n) * 1024 + (lane << 4));
        #pragma unroll
        for (int m = 0; m < FM; ++m)
            #pragma unroll
            for (int n = 0; n < FN; ++n)
                acc[m][n] = __builtin_amdgcn_mfma_f32_16x16x32_bf16(
                    af[m], bq[n], acc[m][n], 0, 0, 0);
        if (t + 1 < nt) { __syncthreads(); cur ^= 1; }
    }
#undef STAGE

    int lq = (lane >> 4) * 4;
    #pragma unroll
    for (int m = 0; m < FM; ++m) {
        #pragma unroll
        for (int n = 0; n < FN; ++n) {
            int colI = n0 + wc * WN + n * 16 + lr;
            #pragma unroll
            for (int j = 0; j < 4; ++j) {
                int rowI = m0 + wr * WM + m * 16 + lq + j;
                float v = acc[m][n][j];
                if (EPI != 0) v += bias[colI];
                if (EPI == 2) v = 0.5f * v * (1.0f + erff(v * 0.70710678118654752f));
                if (EPI == 3) v = fmaxf(v, 0.0f);
                long off = (long)rowI * N + colI;
                if (EPI == 1)      Cf[off] = v + resid[off];
                else               Ch[off] = (bf16_t)v;
            }
        }
    }
}

// ---------------- fused attention: one block per (batch, head). T=32, HD=64.
__global__ __launch_bounds__(256) void attn_kernel(const bf16_t* __restrict__ qkv,
                                                   bf16_t* __restrict__ o) {
    int bh = blockIdx.x;
    int b  = bh >> 4;
    int hh = bh & 15;
    __shared__ float qs[32][64];
    __shared__ float kt[64][33];
    __shared__ float vs[32][64];
    __shared__ float ps[32][33];
    const bf16_t* base = qkv + (long)b * SEQ * (3 * DIM) + hh * HDIM;
    int tid = threadIdx.x;

    {   // 256 threads cover 32 rows x 8 chunks of 8 elems
        int t = tid >> 3, c = (tid & 7) * 8;
        bf16x8 qv = *(const bf16x8*)(base + (long)t * 3 * DIM + c);
        bf16x8 kv = *(const bf16x8*)(base + (long)t * 3 * DIM + DIM + c);
        bf16x8 vv = *(const bf16x8*)(base + (long)t * 3 * DIM + 2 * DIM + c);
        #pragma unroll
        for (int j = 0; j < 8; ++j) {
            qs[t][c + j] = (float)qv[j];
            kt[c + j][t] = (float)kv[j];
            vs[t][c + j] = (float)vv[j];
        }
    }
    __syncthreads();

    for (int i = tid; i < 1024; i += 256) {
        int r = i >> 5, c = i & 31;
        float acc = 0.f;
        #pragma unroll
        for (int d = 0; d < 64; ++d) acc = fmaf(qs[r][d], kt[d][c], acc);
        ps[r][c] = acc * 0.125f;
    }
    __syncthreads();

    if (tid < 32) {
        float mx = -1e30f;
        for (int c = 0; c < 32; ++c) mx = fmaxf(mx, ps[tid][c]);
        float sum = 0.f;
        for (int c = 0; c < 32; ++c) { float e = expf(ps[tid][c] - mx); ps[tid][c] = e; sum += e; }
        float inv = 1.f / sum;
        for (int c = 0; c < 32; ++c) ps[tid][c] *= inv;
    }
    __syncthreads();

    for (int i = tid; i < 2048; i += 256) {
        int r = i >> 6, d = i & 63;
        float acc = 0.f;
        #pragma unroll
        for (int c = 0; c < 32; ++c) acc = fmaf(ps[r][c], vs[c][d], acc);
        o[(long)b * SEQ * DIM + (long)r * DIM + hh * HDIM + d] = (bf16_t)acc;
    }
}

// ---------------- x_comb -> bf16
__global__ void comb_kernel(const float* __restrict__ h, bf16_t* __restrict__ xc) {
    int i = blockIdx.x * 256 + threadIdx.x;
    int b = i >> 11;
    int c = i & 2047;
    xc[i] = (bf16_t)h[(long)b * (SEQ * DIM) + c];
}

// ---------------- head layer 3: one wave per (n, b), dot-512
__global__ __launch_bounds__(256) void head3_kernel(const bf16_t* __restrict__ h2,
                                                    const float* __restrict__ w3,
                                                    const float* __restrict__ b3,
                                                    float* __restrict__ out) {
    int gid  = blockIdx.x * 256 + threadIdx.x;
    int wave = gid >> 6;
    int lane = gid & 63;
    if (wave >= NHEAD_OUT * BATCH) return;
    int n = wave >> 6;
    int b = wave & 63;
    const bf16_t* a = h2 + ((long)n * BATCH + b) * IDH;
    const float*  w = w3 + (long)n * IDH;
    float acc = 0.f;
    #pragma unroll
    for (int i = lane; i < IDH; i += 64) acc = fmaf((float)a[i], w[i], acc);
    #pragma unroll
    for (int off = 32; off > 0; off >>= 1) acc += __shfl_down(acc, off);
    if (lane == 0) out[b * NHEAD_OUT + n] = acc + b3[n];
}

extern "C" void kernel_launch(void* const* d_in, const int* in_sizes, int n_in,
                              void* d_out, int out_size, void* d_ws, size_t ws_size,
                              hipStream_t stream) {
    const float* x      = (const float*)d_in[0];
    const float* qkv_w  = (const float*)d_in[1];
    const float* out_w  = (const float*)d_in[2];
    const float* out_b  = (const float*)d_in[3];
    const float* attn_g = (const float*)d_in[4];
    const float* attn_b = (const float*)d_in[5];
    const float* ff_g   = (const float*)d_in[6];
    const float* ff_b   = (const float*)d_in[7];
    const float* ff_w1  = (const float*)d_in[8];
    const float* ff_b1  = (const float*)d_in[9];
    const float* ff_w2  = (const float*)d_in[10];
    const float* ff_b2  = (const float*)d_in[11];
    const float* hw1    = (const float*)d_in[12];
    const float* hb1    = (const float*)d_in[13];
    const float* hw2    = (const float*)d_in[14];
    const float* hb2    = (const float*)d_in[15];
    const float* hw3    = (const float*)d_in[16];
    const float* hb3    = (const float*)d_in[17];
    float* out = (float*)d_out;

    char* p = (char*)d_ws;
    float*  h     = (float*)p;            p += (long)TOK * DIM * 4;
    bf16_t* qkvb  = (bf16_t*)p;           p += (long)TOK * 3 * DIM * 2;
    bf16_t* y     = (bf16_t*)p;           p += (long)TOK * DIM * 2;
    bf16_t* ob    = (bf16_t*)p;           p += (long)TOK * DIM * 2;
    bf16_t* ffb   = (bf16_t*)p;           p += (long)TOK * FFD * 2;
    bf16_t* xc    = (bf16_t*)p;           p += (long)BATCH * 2 * DIM * 2;
    bf16_t* h1    = (bf16_t*)p;           p += (long)NHEAD_OUT * BATCH * IDH * 2;
    bf16_t* h2    = (bf16_t*)p;           p += (long)NHEAD_OUT * BATCH * IDH * 2;
    bf16_t* qkvwt = (bf16_t*)p;           p += (long)LAYERS * DIM * 3 * DIM * 2;
    bf16_t* outwt = (bf16_t*)p;           p += (long)LAYERS * DIM * DIM * 2;
    bf16_t* ff1t  = (bf16_t*)p;           p += (long)LAYERS * DIM * FFD * 2;
    bf16_t* ff2t  = (bf16_t*)p;           p += (long)LAYERS * FFD * DIM * 2;
    bf16_t* hw1t  = (bf16_t*)p;           p += (long)NHEAD_OUT * 2 * DIM * IDH * 2;
    bf16_t* hw2t  = (bf16_t*)p;           p += (long)NHEAD_OUT * IDH * IDH * 2;

    // ---- one-time (per call) weight transpose+convert ----
    transpose_cvt<<<dim3(3 * DIM / 32, DIM / 32, LAYERS), 256, 0, stream>>>(qkv_w, qkvwt, DIM, 3 * DIM);
    transpose_cvt<<<dim3(DIM / 32, DIM / 32, LAYERS), 256, 0, stream>>>(out_w, outwt, DIM, DIM);
    transpose_cvt<<<dim3(FFD / 32, DIM / 32, LAYERS), 256, 0, stream>>>(ff_w1, ff1t, DIM, FFD);
    transpose_cvt<<<dim3(DIM / 32, FFD / 32, LAYERS), 256, 0, stream>>>(ff_w2, ff2t, FFD, DIM);
    transpose_cvt<<<dim3(IDH / 32, 2 * DIM / 32, NHEAD_OUT), 256, 0, stream>>>(hw1, hw1t, 2 * DIM, IDH);
    transpose_cvt<<<dim3(IDH / 32, IDH / 32, NHEAD_OUT), 256, 0, stream>>>(hw2, hw2t, IDH, IDH);

    hipMemcpyAsync(h, x, (size_t)TOK * DIM * sizeof(float),
                   hipMemcpyDeviceToDevice, stream);

    for (int l = 0; l < LAYERS; ++l) {
        ln_kernel<true><<<TOK, 256, 0, stream>>>(h, attn_g + l * DIM, attn_b + l * DIM, y);
        gemm_bt<128, 128, 64, 64, 0><<<dim3(3 * DIM / 128, TOK / 128), 256, 0, stream>>>(
            y, qkvwt + (long)l * DIM * 3 * DIM, nullptr, nullptr, qkvb,
            TOK, 3 * DIM, DIM, 0, 0, 0, 0);
        attn_kernel<<<BATCH * NH, 256, 0, stream>>>(qkvb, ob);
        gemm_bt<64, 128, 32, 64, 1><<<dim3(DIM / 128, TOK / 64), 256, 0, stream>>>(
            ob, outwt + (long)l * DIM * DIM, out_b + l * DIM, h, h,
            TOK, DIM, DIM, 0, 0, 0, 0);
        ln_kernel<false><<<TOK, 256, 0, stream>>>(h, ff_g + l * DIM, ff_b + l * DIM, y);
        gemm_bt<128, 128, 64, 64, 2><<<dim3(FFD / 128, TOK / 128), 256, 0, stream>>>(
            y, ff1t + (long)l * DIM * FFD, ff_b1 + l * FFD, nullptr, ffb,
            TOK, FFD, DIM, 0, 0, 0, 0);
        gemm_bt<64, 128, 32, 64, 1><<<dim3(DIM / 128, TOK / 64), 256, 0, stream>>>(
            ffb, ff2t + (long)l * FFD * DIM, ff_b2 + l * DIM, h, h,
            TOK, DIM, FFD, 0, 0, 0, 0);
    }

    comb_kernel<<<(BATCH * 2 * DIM) / 256, 256, 0, stream>>>(h, xc);

    gemm_bt<64, 64, 32, 32, 3><<<dim3(IDH / 64, 1, NHEAD_OUT), 256, 0, stream>>>(
        xc, hw1t, hb1, nullptr, h1,
        BATCH, IDH, 2 * DIM,
        0, (long)2 * DIM * IDH, IDH, (long)BATCH * IDH);
    gemm_bt<64, 64, 32, 32, 3><<<dim3(IDH / 64, 1, NHEAD_OUT), 256, 0, stream>>>(
        h1, hw2t, hb2, nullptr, h2,
        BATCH, IDH, IDH,
        (long)BATCH * IDH, (long)IDH * IDH, IDH, (long)BATCH * IDH);
    head3_kernel<<<(NHEAD_OUT * BATCH * 64) / 256, 256, 0, stream>>>(h2, hw3, hb3, out);
}

// Round 4
// 795.118 us; speedup vs baseline: 1.0860x; 1.0860x over previous
//
#include <hip/hip_runtime.h>
#include <math.h>

static constexpr int BATCH = 64;
static constexpr int SEQ   = 32;
static constexpr int TOK   = BATCH * SEQ;   // 2048
static constexpr int DIM   = 1024;
static constexpr int NH    = 16;
static constexpr int HDIM  = 64;
static constexpr int FFD   = 2048;
static constexpr int LAYERS= 4;
static constexpr int NHEAD_OUT = 26;
static constexpr int IDH   = 512;

typedef __bf16 bf16_t;
typedef __bf16 bf16x8 __attribute__((ext_vector_type(8)));
typedef float  f32x4  __attribute__((ext_vector_type(4)));
typedef unsigned short us4 __attribute__((ext_vector_type(4)));

__device__ __forceinline__ unsigned short f2bfu(float f) {
    return __builtin_bit_cast(unsigned short, (bf16_t)f);
}

__device__ __forceinline__ void gload_lds16(const void* gp, void* lp) {
    __builtin_amdgcn_global_load_lds(
        (const __attribute__((address_space(1))) unsigned int*)gp,
        (__attribute__((address_space(3))) unsigned int*)lp,
        16, 0, 0);
}

// ---------------- block-wide sum (256 threads = 4 waves) ----------------
__device__ __forceinline__ float block_sum(float v, float* red) {
    #pragma unroll
    for (int off = 32; off > 0; off >>= 1) v += __shfl_down(v, off);
    int lane = threadIdx.x & 63;
    int w    = threadIdx.x >> 6;
    if (lane == 0) red[w] = v;
    __syncthreads();
    float t = red[0] + red[1] + red[2] + red[3];
    __syncthreads();
    return t;
}

// ---------------- LayerNorm -> bf16 output
template<bool PRE>
__global__ __launch_bounds__(256) void ln_kernel(const float* __restrict__ x,
                                                 const float* __restrict__ g,
                                                 const float* __restrict__ b,
                                                 bf16_t* __restrict__ y) {
    __shared__ float red[4];
    long row = blockIdx.x;
    const float* xr = x + row * DIM;
    int tid = threadIdx.x;
    float4 v = *(const float4*)(xr + tid * 4);
    if (PRE) {
        float s  = block_sum(v.x + v.y + v.z + v.w, red);
        float mu = s * (1.0f / DIM);
        v.x -= mu; v.y -= mu; v.z -= mu; v.w -= mu;
        float ss = block_sum(v.x*v.x + v.y*v.y + v.z*v.z + v.w*v.w, red);
        float r  = 1.0f / sqrtf(ss * (1.0f / DIM) + 1e-6f);
        v.x *= r; v.y *= r; v.z *= r; v.w *= r;
    }
    float s  = block_sum(v.x + v.y + v.z + v.w, red);
    float mu = s * (1.0f / DIM);
    v.x -= mu; v.y -= mu; v.z -= mu; v.w -= mu;
    float ss = block_sum(v.x*v.x + v.y*v.y + v.z*v.z + v.w*v.w, red);
    float r  = 1.0f / sqrtf(ss * (1.0f / DIM) + 1e-5f);
    float4 gg = *(const float4*)(g + tid * 4);
    float4 bb = *(const float4*)(b + tid * 4);
    us4 o;
    o.x = f2bfu(v.x * r * gg.x + bb.x);
    o.y = f2bfu(v.y * r * gg.y + bb.y);
    o.z = f2bfu(v.z * r * gg.z + bb.z);
    o.w = f2bfu(v.w * r * gg.w + bb.w);
    *(us4*)(y + row * DIM + tid * 4) = o;
}

// ---------------- transpose + fp32->bf16: W[K][N] -> WT[N][K], grouped over z
__global__ __launch_bounds__(256) void transpose_cvt(const float* __restrict__ W,
                                                     bf16_t* __restrict__ WT,
                                                     int K, int N) {
    long g = blockIdx.z;
    W  += g * (long)K * N;
    WT += g * (long)K * N;
    __shared__ float t[32][33];
    int n0 = blockIdx.x * 32, k0 = blockIdx.y * 32;
    int r = threadIdx.x >> 3;          // 0..31
    int c = (threadIdx.x & 7) * 4;     // 0,4,...,28
    float4 v = *(const float4*)(W + (long)(k0 + r) * N + n0 + c);
    t[r][c] = v.x; t[r][c+1] = v.y; t[r][c+2] = v.z; t[r][c+3] = v.w;
    __syncthreads();
    us4 o;
    o.x = f2bfu(t[c+0][r]);
    o.y = f2bfu(t[c+1][r]);
    o.z = f2bfu(t[c+2][r]);
    o.w = f2bfu(t[c+3][r]);
    *(us4*)(WT + (long)(n0 + r) * K + k0 + c) = o;
}

// ---------------- MFMA GEMM: A[M][K] bf16, BT[N][K] bf16, C = A @ B (+epilogue)
// Single-buffered 2-barrier loop (round-2 flow) + fragment-ordered LDS
// (conflict-free ds_read_b128: LDS linear in lane order, global src pre-permuted).
// EPI: 0 = none (bf16 out), 1 = +bias +resid (fp32 out),
//      2 = +bias, gelu (bf16 out), 3 = +bias, relu (bf16 out)
template<int BM, int BN, int WM, int WN, int EPI>
__global__ __launch_bounds__(256) void gemm_bt(
    const bf16_t* __restrict__ A, const bf16_t* __restrict__ BT,
    const float* __restrict__ bias, const float* __restrict__ resid,
    void* __restrict__ Cv,
    int M, int N, int K, long sA, long sB, long sbias, long sC)
{
    constexpr int WAVES_N = BN / WN;
    constexpr int FM = WM / 16, FN = WN / 16;
    constexpr int SA = BM / 16, SB = BN / 16;   // 1KB subtiles per K-step
    long g = blockIdx.z;
    A  += g * sA;
    BT += g * sB;
    if (EPI != 0) bias += g * sbias;
    float*  Cf = (float*)Cv + g * sC;
    bf16_t* Ch = (bf16_t*)Cv + g * sC;

    __shared__ bf16_t As[BM * 32];
    __shared__ bf16_t Bs[BN * 32];

    int tid  = threadIdx.x;
    int wave = tid >> 6, lane = tid & 63;
    int wr = wave / WAVES_N, wc = wave % WAVES_N;
    int m0 = blockIdx.y * BM, n0 = blockIdx.x * BN;

    f32x4 acc[FM][FN];
    #pragma unroll
    for (int m = 0; m < FM; ++m)
        #pragma unroll
        for (int n = 0; n < FN; ++n)
            acc[m][n] = f32x4{0.f, 0.f, 0.f, 0.f};

    const char* Ab = (const char*)A;
    const char* Bb = (const char*)BT;
    long rsb = (long)K * 2;                 // row byte stride
    int  lr  = lane & 15;                   // fragment row within subtile
    int  lkb = (lane >> 4) * 16;            // fragment k-chunk byte offset

    // per-lane global bases, permuted to MFMA fragment order (LDS stays linear)
    const char* Abase = Ab + (long)(m0 + lr) * rsb + lkb;
    const char* Bbase = Bb + (long)(n0 + lr) * rsb + lkb;

    for (int k0 = 0; k0 < K; k0 += 32) {
        long kb = (long)k0 * 2;
        #pragma unroll
        for (int i = 0; i < SA / 4; ++i) {
            int s_ = i * 4 + wave;
            gload_lds16(Abase + (long)s_ * 16 * rsb + kb,
                        (char*)As + s_ * 1024);
        }
        #pragma unroll
        for (int i = 0; i < SB / 4; ++i) {
            int s_ = i * 4 + wave;
            gload_lds16(Bbase + (long)s_ * 16 * rsb + kb,
                        (char*)Bs + s_ * 1024);
        }
        __syncthreads();
        bf16x8 af[FM], bq[FN];
        #pragma unroll
        for (int m = 0; m < FM; ++m)
            af[m] = *(const bf16x8*)((const char*)As +
                                     (wr * FM + m) * 1024 + (lane << 4));
        #pragma unroll
        for (int n = 0; n < FN; ++n)
            bq[n] = *(const bf16x8*)((const char*)Bs +
                                     (wc * FN + n) * 1024 + (lane << 4));
        #pragma unroll
        for (int m = 0; m < FM; ++m)
            #pragma unroll
            for (int n = 0; n < FN; ++n)
                acc[m][n] = __builtin_amdgcn_mfma_f32_16x16x32_bf16(
                    af[m], bq[n], acc[m][n], 0, 0, 0);
        __syncthreads();
    }

    int lq = (lane >> 4) * 4;
    #pragma unroll
    for (int m = 0; m < FM; ++m) {
        #pragma unroll
        for (int n = 0; n < FN; ++n) {
            int colI = n0 + wc * WN + n * 16 + lr;
            #pragma unroll
            for (int j = 0; j < 4; ++j) {
                int rowI = m0 + wr * WM + m * 16 + lq + j;
                float v = acc[m][n][j];
                if (EPI != 0) v += bias[colI];
                if (EPI == 2) v = 0.5f * v * (1.0f + erff(v * 0.70710678118654752f));
                if (EPI == 3) v = fmaxf(v, 0.0f);
                long off = (long)rowI * N + colI;
                if (EPI == 1)      Cf[off] = v + resid[off];
                else               Ch[off] = (bf16_t)v;
            }
        }
    }
}

// ---------------- fused attention: one block per (batch, head). T=32, HD=64.
__global__ __launch_bounds__(256) void attn_kernel(const bf16_t* __restrict__ qkv,
                                                   bf16_t* __restrict__ o) {
    int bh = blockIdx.x;
    int b  = bh >> 4;
    int hh = bh & 15;
    __shared__ float qs[32][64];
    __shared__ float kt[64][33];
    __shared__ float vs[32][64];
    __shared__ float ps[32][33];
    const bf16_t* base = qkv + (long)b * SEQ * (3 * DIM) + hh * HDIM;
    int tid = threadIdx.x;

    {   // 256 threads cover 32 rows x 8 chunks of 8 elems
        int t = tid >> 3, c = (tid & 7) * 8;
        bf16x8 qv = *(const bf16x8*)(base + (long)t * 3 * DIM + c);
        bf16x8 kv = *(const bf16x8*)(base + (long)t * 3 * DIM + DIM + c);
        bf16x8 vv = *(const bf16x8*)(base + (long)t * 3 * DIM + 2 * DIM + c);
        #pragma unroll
        for (int j = 0; j < 8; ++j) {
            qs[t][c + j] = (float)qv[j];
            kt[c + j][t] = (float)kv[j];
            vs[t][c + j] = (float)vv[j];
        }
    }
    __syncthreads();

    for (int i = tid; i < 1024; i += 256) {
        int r = i >> 5, c = i & 31;
        float acc = 0.f;
        #pragma unroll
        for (int d = 0; d < 64; ++d) acc = fmaf(qs[r][d], kt[d][c], acc);
        ps[r][c] = acc * 0.125f;
    }
    __syncthreads();

    if (tid < 32) {
        float mx = -1e30f;
        for (int c = 0; c < 32; ++c) mx = fmaxf(mx, ps[tid][c]);
        float sum = 0.f;
        for (int c = 0; c < 32; ++c) { float e = expf(ps[tid][c] - mx); ps[tid][c] = e; sum += e; }
        float inv = 1.f / sum;
        for (int c = 0; c < 32; ++c) ps[tid][c] *= inv;
    }
    __syncthreads();

    for (int i = tid; i < 2048; i += 256) {
        int r = i >> 6, d = i & 63;
        float acc = 0.f;
        #pragma unroll
        for (int c = 0; c < 32; ++c) acc = fmaf(ps[r][c], vs[c][d], acc);
        o[(long)b * SEQ * DIM + (long)r * DIM + hh * HDIM + d] = (bf16_t)acc;
    }
}

// ---------------- x_comb -> bf16
__global__ void comb_kernel(const float* __restrict__ h, bf16_t* __restrict__ xc) {
    int i = blockIdx.x * 256 + threadIdx.x;
    int b = i >> 11;
    int c = i & 2047;
    xc[i] = (bf16_t)h[(long)b * (SEQ * DIM) + c];
}

// ---------------- head layer 3: one wave per (n, b), dot-512
__global__ __launch_bounds__(256) void head3_kernel(const bf16_t* __restrict__ h2,
                                                    const float* __restrict__ w3,
                                                    const float* __restrict__ b3,
                                                    float* __restrict__ out) {
    int gid  = blockIdx.x * 256 + threadIdx.x;
    int wave = gid >> 6;
    int lane = gid & 63;
    if (wave >= NHEAD_OUT * BATCH) return;
    int n = wave >> 6;
    int b = wave & 63;
    const bf16_t* a = h2 + ((long)n * BATCH + b) * IDH;
    const float*  w = w3 + (long)n * IDH;
    float acc = 0.f;
    #pragma unroll
    for (int i = lane; i < IDH; i += 64) acc = fmaf((float)a[i], w[i], acc);
    #pragma unroll
    for (int off = 32; off > 0; off >>= 1) acc += __shfl_down(acc, off);
    if (lane == 0) out[b * NHEAD_OUT + n] = acc + b3[n];
}

extern "C" void kernel_launch(void* const* d_in, const int* in_sizes, int n_in,
                              void* d_out, int out_size, void* d_ws, size_t ws_size,
                              hipStream_t stream) {
    const float* x      = (const float*)d_in[0];
    const float* qkv_w  = (const float*)d_in[1];
    const float* out_w  = (const float*)d_in[2];
    const float* out_b  = (const float*)d_in[3];
    const float* attn_g = (const float*)d_in[4];
    const float* attn_b = (const float*)d_in[5];
    const float* ff_g   = (const float*)d_in[6];
    const float* ff_b   = (const float*)d_in[7];
    const float* ff_w1  = (const float*)d_in[8];
    const float* ff_b1  = (const float*)d_in[9];
    const float* ff_w2  = (const float*)d_in[10];
    const float* ff_b2  = (const float*)d_in[11];
    const float* hw1    = (const float*)d_in[12];
    const float* hb1    = (const float*)d_in[13];
    const float* hw2    = (const float*)d_in[14];
    const float* hb2    = (const float*)d_in[15];
    const float* hw3    = (const float*)d_in[16];
    const float* hb3    = (const float*)d_in[17];
    float* out = (float*)d_out;

    char* p = (char*)d_ws;
    float*  h     = (float*)p;            p += (long)TOK * DIM * 4;
    bf16_t* qkvb  = (bf16_t*)p;           p += (long)TOK * 3 * DIM * 2;
    bf16_t* y     = (bf16_t*)p;           p += (long)TOK * DIM * 2;
    bf16_t* ob    = (bf16_t*)p;           p += (long)TOK * DIM * 2;
    bf16_t* ffb   = (bf16_t*)p;           p += (long)TOK * FFD * 2;
    bf16_t* xc    = (bf16_t*)p;           p += (long)BATCH * 2 * DIM * 2;
    bf16_t* h1    = (bf16_t*)p;           p += (long)NHEAD_OUT * BATCH * IDH * 2;
    bf16_t* h2    = (bf16_t*)p;           p += (long)NHEAD_OUT * BATCH * IDH * 2;
    bf16_t* qkvwt = (bf16_t*)p;           p += (long)LAYERS * DIM * 3 * DIM * 2;
    bf16_t* outwt = (bf16_t*)p;           p += (long)LAYERS * DIM * DIM * 2;
    bf16_t* ff1t  = (bf16_t*)p;           p += (long)LAYERS * DIM * FFD * 2;
    bf16_t* ff2t  = (bf16_t*)p;           p += (long)LAYERS * FFD * DIM * 2;
    bf16_t* hw1t  = (bf16_t*)p;           p += (long)NHEAD_OUT * 2 * DIM * IDH * 2;
    bf16_t* hw2t  = (bf16_t*)p;           p += (long)NHEAD_OUT * IDH * IDH * 2;

    // ---- one-time (per call) weight transpose+convert ----
    transpose_cvt<<<dim3(3 * DIM / 32, DIM / 32, LAYERS), 256, 0, stream>>>(qkv_w, qkvwt, DIM, 3 * DIM);
    transpose_cvt<<<dim3(DIM / 32, DIM / 32, LAYERS), 256, 0, stream>>>(out_w, outwt, DIM, DIM);
    transpose_cvt<<<dim3(FFD / 32, DIM / 32, LAYERS), 256, 0, stream>>>(ff_w1, ff1t, DIM, FFD);
    transpose_cvt<<<dim3(DIM / 32, FFD / 32, LAYERS), 256, 0, stream>>>(ff_w2, ff2t, FFD, DIM);
    transpose_cvt<<<dim3(IDH / 32, 2 * DIM / 32, NHEAD_OUT), 256, 0, stream>>>(hw1, hw1t, 2 * DIM, IDH);
    transpose_cvt<<<dim3(IDH / 32, IDH / 32, NHEAD_OUT), 256, 0, stream>>>(hw2, hw2t, IDH, IDH);

    hipMemcpyAsync(h, x, (size_t)TOK * DIM * sizeof(float),
                   hipMemcpyDeviceToDevice, stream);

    for (int l = 0; l < LAYERS; ++l) {
        ln_kernel<true><<<TOK, 256, 0, stream>>>(h, attn_g + l * DIM, attn_b + l * DIM, y);
        // qkv: M=2048, N=3072, K=1024  -> 64x128 tiles, 768 blocks (3/CU)
        gemm_bt<64, 128, 32, 64, 0><<<dim3(3 * DIM / 128, TOK / 64), 256, 0, stream>>>(
            y, qkvwt + (long)l * DIM * 3 * DIM, nullptr, nullptr, qkvb,
            TOK, 3 * DIM, DIM, 0, 0, 0, 0);
        attn_kernel<<<BATCH * NH, 256, 0, stream>>>(qkvb, ob);
        // out-proj: M=2048, N=1024, K=1024 -> 64x64 tiles, 512 blocks (2/CU)
        gemm_bt<64, 64, 32, 32, 1><<<dim3(DIM / 64, TOK / 64), 256, 0, stream>>>(
            ob, outwt + (long)l * DIM * DIM, out_b + l * DIM, h, h,
            TOK, DIM, DIM, 0, 0, 0, 0);
        ln_kernel<false><<<TOK, 256, 0, stream>>>(h, ff_g + l * DIM, ff_b + l * DIM, y);
        // ff1: M=2048, N=2048, K=1024 -> 64x128 tiles, 512 blocks (2/CU)
        gemm_bt<64, 128, 32, 64, 2><<<dim3(FFD / 128, TOK / 64), 256, 0, stream>>>(
            y, ff1t + (long)l * DIM * FFD, ff_b1 + l * FFD, nullptr, ffb,
            TOK, FFD, DIM, 0, 0, 0, 0);
        // ff2: M=2048, N=1024, K=2048 -> 64x64 tiles, 512 blocks (2/CU)
        gemm_bt<64, 64, 32, 32, 1><<<dim3(DIM / 64, TOK / 64), 256, 0, stream>>>(
            ffb, ff2t + (long)l * FFD * DIM, ff_b2 + l * DIM, h, h,
            TOK, DIM, FFD, 0, 0, 0, 0);
    }

    comb_kernel<<<(BATCH * 2 * DIM) / 256, 256, 0, stream>>>(h, xc);

    gemm_bt<64, 64, 32, 32, 3><<<dim3(IDH / 64, 1, NHEAD_OUT), 256, 0, stream>>>(
        xc, hw1t, hb1, nullptr, h1,
        BATCH, IDH, 2 * DIM,
        0, (long)2 * DIM * IDH, IDH, (long)BATCH * IDH);
    gemm_bt<64, 64, 32, 32, 3><<<dim3(IDH / 64, 1, NHEAD_OUT), 256, 0, stream>>>(
        h1, hw2t, hb2, nullptr, h2,
        BATCH, IDH, IDH,
        (long)BATCH * IDH, (long)IDH * IDH, IDH, (long)BATCH * IDH);
    head3_kernel<<<(NHEAD_OUT * BATCH * 64) / 256, 256, 0, stream>>>(h2, hw3, hb3, out);
}

// Round 5
// 719.596 us; speedup vs baseline: 1.2000x; 1.1050x over previous
//
#include <hip/hip_runtime.h>
#include <math.h>

static constexpr int BATCH = 64;
static constexpr int SEQ   = 32;
static constexpr int TOK   = BATCH * SEQ;   // 2048
static constexpr int DIM   = 1024;
static constexpr int NH    = 16;
static constexpr int HDIM  = 64;
static constexpr int FFD   = 2048;
static constexpr int LAYERS= 4;
static constexpr int NHEAD_OUT = 26;
static constexpr int IDH   = 512;

typedef __bf16 bf16_t;
typedef __bf16 bf16x8 __attribute__((ext_vector_type(8)));
typedef float  f32x4  __attribute__((ext_vector_type(4)));
typedef unsigned short us4 __attribute__((ext_vector_type(4)));
typedef unsigned short us8 __attribute__((ext_vector_type(8)));

__device__ __forceinline__ unsigned short f2bfu(float f) {
    return __builtin_bit_cast(unsigned short, (bf16_t)f);
}

__device__ __forceinline__ void gload_lds16(const void* gp, void* lp) {
    __builtin_amdgcn_global_load_lds(
        (const __attribute__((address_space(1))) unsigned int*)gp,
        (__attribute__((address_space(3))) unsigned int*)lp,
        16, 0, 0);
}

// ---------------- block-wide sum (256 threads = 4 waves) ----------------
__device__ __forceinline__ float block_sum(float v, float* red) {
    #pragma unroll
    for (int off = 32; off > 0; off >>= 1) v += __shfl_down(v, off);
    int lane = threadIdx.x & 63;
    int w    = threadIdx.x >> 6;
    if (lane == 0) red[w] = v;
    __syncthreads();
    float t = red[0] + red[1] + red[2] + red[3];
    __syncthreads();
    return t;
}

// ---------------- LayerNorm -> bf16 output
template<bool PRE>
__global__ __launch_bounds__(256) void ln_kernel(const float* __restrict__ x,
                                                 const float* __restrict__ g,
                                                 const float* __restrict__ b,
                                                 bf16_t* __restrict__ y) {
    __shared__ float red[4];
    long row = blockIdx.x;
    const float* xr = x + row * DIM;
    int tid = threadIdx.x;
    float4 v = *(const float4*)(xr + tid * 4);
    if (PRE) {
        float s  = block_sum(v.x + v.y + v.z + v.w, red);
        float mu = s * (1.0f / DIM);
        v.x -= mu; v.y -= mu; v.z -= mu; v.w -= mu;
        float ss = block_sum(v.x*v.x + v.y*v.y + v.z*v.z + v.w*v.w, red);
        float r  = 1.0f / sqrtf(ss * (1.0f / DIM) + 1e-6f);
        v.x *= r; v.y *= r; v.z *= r; v.w *= r;
    }
    float s  = block_sum(v.x + v.y + v.z + v.w, red);
    float mu = s * (1.0f / DIM);
    v.x -= mu; v.y -= mu; v.z -= mu; v.w -= mu;
    float ss = block_sum(v.x*v.x + v.y*v.y + v.z*v.z + v.w*v.w, red);
    float r  = 1.0f / sqrtf(ss * (1.0f / DIM) + 1e-5f);
    float4 gg = *(const float4*)(g + tid * 4);
    float4 bb = *(const float4*)(b + tid * 4);
    us4 o;
    o.x = f2bfu(v.x * r * gg.x + bb.x);
    o.y = f2bfu(v.y * r * gg.y + bb.y);
    o.z = f2bfu(v.z * r * gg.z + bb.z);
    o.w = f2bfu(v.w * r * gg.w + bb.w);
    *(us4*)(y + row * DIM + tid * 4) = o;
}

// ---------------- merged transpose+cvt: all 6 weight groups in one launch
// 64x64 tiles, XOR-swizzled fp32 LDS (<=2-way conflicts), us8 writes.
struct TxPack {
    const float* src[6];
    bf16_t*      dst[6];
    int K[6], N[6];
    int blk0[6];
};

__global__ __launch_bounds__(256) void tx64(TxPack p) {
    int bid = blockIdx.x;
    int s = 0;
    #pragma unroll
    for (int i = 1; i < 6; ++i) if (bid >= p.blk0[i]) s = i;
    int local = bid - p.blk0[s];
    int K = p.K[s], N = p.N[s];
    int ntn = N >> 6, ntk = K >> 6, tpg = ntn * ntk;
    int g  = local / tpg;
    int t_ = local - g * tpg;
    int kt = t_ / ntn, nt = t_ - kt * ntn;
    const float* src = p.src[s] + (long)g * K * N;
    bf16_t*      dst = p.dst[s] + (long)g * K * N;
    int k0 = kt * 64, n0 = nt * 64;

    __shared__ float t[64][68];
    int tid = threadIdx.x;
    int kr = tid >> 4;             // 0..15
    int nc = (tid & 15) * 4;       // 0..60
    #pragma unroll
    for (int i = 0; i < 4; ++i) {
        int k = kr + i * 16;
        float4 v = *(const float4*)(src + (long)(k0 + k) * N + n0 + nc);
        int sw = (k >> 3) & 7;
        *(float4*)&t[k][nc ^ (sw << 3)] = v;
    }
    __syncthreads();
    int kc = tid & 7;              // k-chunk (8 elems)
    int nr = tid >> 3;             // 0..31
    #pragma unroll
    for (int h = 0; h < 2; ++h) {
        int n = nr + h * 32;
        us8 o;
        #pragma unroll
        for (int j = 0; j < 8; ++j)
            o[j] = f2bfu(t[kc * 8 + j][n ^ (kc << 3)]);
        *(us8*)(dst + (long)(n0 + n) * K + k0 + kc * 8) = o;
    }
}

// ---------------- MFMA GEMM: A[M][K] bf16, BT[N][K] bf16, C = A @ B (+epilogue)
// BK=64 (2 fragment-halves per barrier pair), single-buffer 2-barrier loop,
// fragment-ordered conflict-free LDS (linear dest, pre-permuted global src).
// EPI: 0 = none (bf16 out), 1 = +bias +resid (fp32 out),
//      2 = +bias, gelu (bf16 out), 3 = +bias, relu (bf16 out)
template<int BM, int BN, int WM, int WN, int EPI>
__global__ __launch_bounds__(256) void gemm_bt(
    const bf16_t* __restrict__ A, const bf16_t* __restrict__ BT,
    const float* __restrict__ bias, const float* __restrict__ resid,
    void* __restrict__ Cv,
    int M, int N, int K, long sA, long sB, long sbias, long sC)
{
    constexpr int WAVES_N = BN / WN;
    constexpr int FM = WM / 16, FN = WN / 16;
    long g = blockIdx.z;
    A  += g * sA;
    BT += g * sB;
    if (EPI != 0) bias += g * sbias;
    float*  Cf = (float*)Cv + g * sC;
    bf16_t* Ch = (bf16_t*)Cv + g * sC;

    __shared__ bf16_t As[BM * 64];
    __shared__ bf16_t Bs[BN * 64];

    int tid  = threadIdx.x;
    int wave = tid >> 6, lane = tid & 63;
    int wr = wave / WAVES_N, wc = wave % WAVES_N;
    int m0 = blockIdx.y * BM, n0 = blockIdx.x * BN;

    f32x4 acc[FM][FN];
    #pragma unroll
    for (int m = 0; m < FM; ++m)
        #pragma unroll
        for (int n = 0; n < FN; ++n)
            acc[m][n] = f32x4{0.f, 0.f, 0.f, 0.f};

    long rsb = (long)K * 2;                 // row byte stride
    int  lr  = lane & 15;                   // fragment row within subtile
    int  lkb = (lane >> 4) * 16;            // fragment k-chunk byte offset

    // per-lane global bases, permuted to MFMA fragment order (LDS stays linear)
    const char* Abase = (const char*)A + (long)(m0 + lr) * rsb + lkb;
    const char* Bbase = (const char*)BT + (long)(n0 + lr) * rsb + lkb;

    for (int k0 = 0; k0 < K; k0 += 64) {
        long kb = (long)k0 * 2;
        #pragma unroll
        for (int i = 0; i < BM / 32; ++i) {
            int b = i * 4 + wave;           // subtile-half index: s=b>>1, h=b&1
            gload_lds16(Abase + (long)(b >> 1) * 16 * rsb + (b & 1) * 64 + kb,
                        (char*)As + b * 1024);
        }
        #pragma unroll
        for (int i = 0; i < BN / 32; ++i) {
            int b = i * 4 + wave;
            gload_lds16(Bbase + (long)(b >> 1) * 16 * rsb + (b & 1) * 64 + kb,
                        (char*)Bs + b * 1024);
        }
        __syncthreads();
        bf16x8 af[FM][2], bq[FN][2];
        #pragma unroll
        for (int m = 0; m < FM; ++m)
            #pragma unroll
            for (int h = 0; h < 2; ++h)
                af[m][h] = *(const bf16x8*)((const char*)As +
                           ((wr * FM + m) * 2 + h) * 1024 + (lane << 4));
        #pragma unroll
        for (int n = 0; n < FN; ++n)
            #pragma unroll
            for (int h = 0; h < 2; ++h)
                bq[n][h] = *(const bf16x8*)((const char*)Bs +
                           ((wc * FN + n) * 2 + h) * 1024 + (lane << 4));
        #pragma unroll
        for (int h = 0; h < 2; ++h)
            #pragma unroll
            for (int m = 0; m < FM; ++m)
                #pragma unroll
                for (int n = 0; n < FN; ++n)
                    acc[m][n] = __builtin_amdgcn_mfma_f32_16x16x32_bf16(
                        af[m][h], bq[n][h], acc[m][n], 0, 0, 0);
        __syncthreads();
    }

    int lq = (lane >> 4) * 4;
    #pragma unroll
    for (int m = 0; m < FM; ++m) {
        #pragma unroll
        for (int n = 0; n < FN; ++n) {
            int colI = n0 + wc * WN + n * 16 + lr;
            #pragma unroll
            for (int j = 0; j < 4; ++j) {
                int rowI = m0 + wr * WM + m * 16 + lq + j;
                float v = acc[m][n][j];
                if (EPI != 0) v += bias[colI];
                if (EPI == 2) v = 0.5f * v * (1.0f + erff(v * 0.70710678118654752f));
                if (EPI == 3) v = fmaxf(v, 0.0f);
                long off = (long)rowI * N + colI;
                if (EPI == 1)      Cf[off] = v + resid[off];
                else               Ch[off] = (bf16_t)v;
            }
        }
    }
}

// ---------------- fused attention: one block per (batch, head). T=32, HD=64.
__global__ __launch_bounds__(256) void attn_kernel(const bf16_t* __restrict__ qkv,
                                                   bf16_t* __restrict__ o) {
    int bh = blockIdx.x;
    int b  = bh >> 4;
    int hh = bh & 15;
    __shared__ float qs[32][64];
    __shared__ float kt[64][33];
    __shared__ float vs[32][64];
    __shared__ float ps[32][33];
    const bf16_t* base = qkv + (long)b * SEQ * (3 * DIM) + hh * HDIM;
    int tid = threadIdx.x;

    {   // 256 threads cover 32 rows x 8 chunks of 8 elems
        int t = tid >> 3, c = (tid & 7) * 8;
        bf16x8 qv = *(const bf16x8*)(base + (long)t * 3 * DIM + c);
        bf16x8 kv = *(const bf16x8*)(base + (long)t * 3 * DIM + DIM + c);
        bf16x8 vv = *(const bf16x8*)(base + (long)t * 3 * DIM + 2 * DIM + c);
        #pragma unroll
        for (int j = 0; j < 8; ++j) {
            qs[t][c + j] = (float)qv[j];
            kt[c + j][t] = (float)kv[j];
            vs[t][c + j] = (float)vv[j];
        }
    }
    __syncthreads();

    for (int i = tid; i < 1024; i += 256) {
        int r = i >> 5, c = i & 31;
        float acc = 0.f;
        #pragma unroll
        for (int d = 0; d < 64; ++d) acc = fmaf(qs[r][d], kt[d][c], acc);
        ps[r][c] = acc * 0.125f;
    }
    __syncthreads();

    if (tid < 32) {
        float mx = -1e30f;
        for (int c = 0; c < 32; ++c) mx = fmaxf(mx, ps[tid][c]);
        float sum = 0.f;
        for (int c = 0; c < 32; ++c) { float e = expf(ps[tid][c] - mx); ps[tid][c] = e; sum += e; }
        float inv = 1.f / sum;
        for (int c = 0; c < 32; ++c) ps[tid][c] *= inv;
    }
    __syncthreads();

    for (int i = tid; i < 2048; i += 256) {
        int r = i >> 6, d = i & 63;
        float acc = 0.f;
        #pragma unroll
        for (int c = 0; c < 32; ++c) acc = fmaf(ps[r][c], vs[c][d], acc);
        o[(long)b * SEQ * DIM + (long)r * DIM + hh * HDIM + d] = (bf16_t)acc;
    }
}

// ---------------- x_comb -> bf16
__global__ void comb_kernel(const float* __restrict__ h, bf16_t* __restrict__ xc) {
    int i = blockIdx.x * 256 + threadIdx.x;
    int b = i >> 11;
    int c = i & 2047;
    xc[i] = (bf16_t)h[(long)b * (SEQ * DIM) + c];
}

// ---------------- head layer 3: one wave per (n, b), dot-512
__global__ __launch_bounds__(256) void head3_kernel(const bf16_t* __restrict__ h2,
                                                    const float* __restrict__ w3,
                                                    const float* __restrict__ b3,
                                                    float* __restrict__ out) {
    int gid  = blockIdx.x * 256 + threadIdx.x;
    int wave = gid >> 6;
    int lane = gid & 63;
    if (wave >= NHEAD_OUT * BATCH) return;
    int n = wave >> 6;
    int b = wave & 63;
    const bf16_t* a = h2 + ((long)n * BATCH + b) * IDH;
    const float*  w = w3 + (long)n * IDH;
    float acc = 0.f;
    #pragma unroll
    for (int i = lane; i < IDH; i += 64) acc = fmaf((float)a[i], w[i], acc);
    #pragma unroll
    for (int off = 32; off > 0; off >>= 1) acc += __shfl_down(acc, off);
    if (lane == 0) out[b * NHEAD_OUT + n] = acc + b3[n];
}

extern "C" void kernel_launch(void* const* d_in, const int* in_sizes, int n_in,
                              void* d_out, int out_size, void* d_ws, size_t ws_size,
                              hipStream_t stream) {
    const float* x      = (const float*)d_in[0];
    const float* qkv_w  = (const float*)d_in[1];
    const float* out_w  = (const float*)d_in[2];
    const float* out_b  = (const float*)d_in[3];
    const float* attn_g = (const float*)d_in[4];
    const float* attn_b = (const float*)d_in[5];
    const float* ff_g   = (const float*)d_in[6];
    const float* ff_b   = (const float*)d_in[7];
    const float* ff_w1  = (const float*)d_in[8];
    const float* ff_b1  = (const float*)d_in[9];
    const float* ff_w2  = (const float*)d_in[10];
    const float* ff_b2  = (const float*)d_in[11];
    const float* hw1    = (const float*)d_in[12];
    const float* hb1    = (const float*)d_in[13];
    const float* hw2    = (const float*)d_in[14];
    const float* hb2    = (const float*)d_in[15];
    const float* hw3    = (const float*)d_in[16];
    const float* hb3    = (const float*)d_in[17];
    float* out = (float*)d_out;

    char* p = (char*)d_ws;
    float*  h     = (float*)p;            p += (long)TOK * DIM * 4;
    bf16_t* qkvb  = (bf16_t*)p;           p += (long)TOK * 3 * DIM * 2;
    bf16_t* y     = (bf16_t*)p;           p += (long)TOK * DIM * 2;
    bf16_t* ob    = (bf16_t*)p;           p += (long)TOK * DIM * 2;
    bf16_t* ffb   = (bf16_t*)p;           p += (long)TOK * FFD * 2;
    bf16_t* xc    = (bf16_t*)p;           p += (long)BATCH * 2 * DIM * 2;
    bf16_t* h1    = (bf16_t*)p;           p += (long)NHEAD_OUT * BATCH * IDH * 2;
    bf16_t* h2    = (bf16_t*)p;           p += (long)NHEAD_OUT * BATCH * IDH * 2;
    bf16_t* qkvwt = (bf16_t*)p;           p += (long)LAYERS * DIM * 3 * DIM * 2;
    bf16_t* outwt = (bf16_t*)p;           p += (long)LAYERS * DIM * DIM * 2;
    bf16_t* ff1t  = (bf16_t*)p;           p += (long)LAYERS * DIM * FFD * 2;
    bf16_t* ff2t  = (bf16_t*)p;           p += (long)LAYERS * FFD * DIM * 2;
    bf16_t* hw1t  = (bf16_t*)p;           p += (long)NHEAD_OUT * 2 * DIM * IDH * 2;
    bf16_t* hw2t  = (bf16_t*)p;           p += (long)NHEAD_OUT * IDH * IDH * 2;

    // ---- merged weight transpose+convert (single launch) ----
    TxPack tp;
    tp.src[0] = qkv_w; tp.dst[0] = qkvwt; tp.K[0] = DIM;     tp.N[0] = 3 * DIM;
    tp.src[1] = out_w; tp.dst[1] = outwt; tp.K[1] = DIM;     tp.N[1] = DIM;
    tp.src[2] = ff_w1; tp.dst[2] = ff1t;  tp.K[2] = DIM;     tp.N[2] = FFD;
    tp.src[3] = ff_w2; tp.dst[3] = ff2t;  tp.K[3] = FFD;     tp.N[3] = DIM;
    tp.src[4] = hw1;   tp.dst[4] = hw1t;  tp.K[4] = 2 * DIM; tp.N[4] = IDH;
    tp.src[5] = hw2;   tp.dst[5] = hw2t;  tp.K[5] = IDH;     tp.N[5] = IDH;
    int G[6] = {LAYERS, LAYERS, LAYERS, LAYERS, NHEAD_OUT, NHEAD_OUT};
    int nblk = 0;
    for (int i = 0; i < 6; ++i) {
        tp.blk0[i] = nblk;
        nblk += G[i] * (tp.K[i] >> 6) * (tp.N[i] >> 6);
    }
    tx64<<<nblk, 256, 0, stream>>>(tp);

    hipMemcpyAsync(h, x, (size_t)TOK * DIM * sizeof(float),
                   hipMemcpyDeviceToDevice, stream);

    for (int l = 0; l < LAYERS; ++l) {
        ln_kernel<true><<<TOK, 256, 0, stream>>>(h, attn_g + l * DIM, attn_b + l * DIM, y);
        // qkv: M=2048, N=3072 -> 64x128 tiles, 768 blocks
        gemm_bt<64, 128, 32, 64, 0><<<dim3(3 * DIM / 128, TOK / 64), 256, 0, stream>>>(
            y, qkvwt + (long)l * DIM * 3 * DIM, nullptr, nullptr, qkvb,
            TOK, 3 * DIM, DIM, 0, 0, 0, 0);
        attn_kernel<<<BATCH * NH, 256, 0, stream>>>(qkvb, ob);
        // out-proj: 64x64 tiles, 512 blocks
        gemm_bt<64, 64, 32, 32, 1><<<dim3(DIM / 64, TOK / 64), 256, 0, stream>>>(
            ob, outwt + (long)l * DIM * DIM, out_b + l * DIM, h, h,
            TOK, DIM, DIM, 0, 0, 0, 0);
        ln_kernel<false><<<TOK, 256, 0, stream>>>(h, ff_g + l * DIM, ff_b + l * DIM, y);
        // ff1: 64x128 tiles, 512 blocks
        gemm_bt<64, 128, 32, 64, 2><<<dim3(FFD / 128, TOK / 64), 256, 0, stream>>>(
            y, ff1t + (long)l * DIM * FFD, ff_b1 + l * FFD, nullptr, ffb,
            TOK, FFD, DIM, 0, 0, 0, 0);
        // ff2: 64x64 tiles, 512 blocks
        gemm_bt<64, 64, 32, 32, 1><<<dim3(DIM / 64, TOK / 64), 256, 0, stream>>>(
            ffb, ff2t + (long)l * FFD * DIM, ff_b2 + l * DIM, h, h,
            TOK, DIM, FFD, 0, 0, 0, 0);
    }

    comb_kernel<<<(BATCH * 2 * DIM) / 256, 256, 0, stream>>>(h, xc);

    gemm_bt<64, 64, 32, 32, 3><<<dim3(IDH / 64, 1, NHEAD_OUT), 256, 0, stream>>>(
        xc, hw1t, hb1, nullptr, h1,
        BATCH, IDH, 2 * DIM,
        0, (long)2 * DIM * IDH, IDH, (long)BATCH * IDH);
    gemm_bt<64, 64, 32, 32, 3><<<dim3(IDH / 64, 1, NHEAD_OUT), 256, 0, stream>>>(
        h1, hw2t, hb2, nullptr, h2,
        BATCH, IDH, IDH,
        (long)BATCH * IDH, (long)IDH * IDH, IDH, (long)BATCH * IDH);
    head3_kernel<<<(NHEAD_OUT * BATCH * 64) / 256, 256, 0, stream>>>(h2, hw3, hb3, out);
}

// Round 6
// 713.671 us; speedup vs baseline: 1.2099x; 1.0083x over previous
//
#include <hip/hip_runtime.h>
#include <math.h>

static constexpr int BATCH = 64;
static constexpr int SEQ   = 32;
static constexpr int TOK   = BATCH * SEQ;   // 2048
static constexpr int DIM   = 1024;
static constexpr int NH    = 16;
static constexpr int HDIM  = 64;
static constexpr int FFD   = 2048;
static constexpr int LAYERS= 4;
static constexpr int NHEAD_OUT = 26;
static constexpr int IDH   = 512;

typedef __bf16 bf16_t;
typedef __bf16 bf16x8 __attribute__((ext_vector_type(8)));
typedef float  f32x4  __attribute__((ext_vector_type(4)));
typedef float  f32x16 __attribute__((ext_vector_type(16)));
typedef unsigned short us4 __attribute__((ext_vector_type(4)));
typedef unsigned short us8 __attribute__((ext_vector_type(8)));

__device__ __forceinline__ unsigned short f2bfu(float f) {
    return __builtin_bit_cast(unsigned short, (bf16_t)f);
}

__device__ __forceinline__ void gload_lds16(const void* gp, void* lp) {
    __builtin_amdgcn_global_load_lds(
        (const __attribute__((address_space(1))) unsigned int*)gp,
        (__attribute__((address_space(3))) unsigned int*)lp,
        16, 0, 0);
}

// ---------------- block-wide sum (256 threads = 4 waves) ----------------
__device__ __forceinline__ float block_sum(float v, float* red) {
    #pragma unroll
    for (int off = 32; off > 0; off >>= 1) v += __shfl_down(v, off);
    int lane = threadIdx.x & 63;
    int w    = threadIdx.x >> 6;
    if (lane == 0) red[w] = v;
    __syncthreads();
    float t = red[0] + red[1] + red[2] + red[3];
    __syncthreads();
    return t;
}

// ---------------- LayerNorm -> bf16 output
template<bool PRE>
__global__ __launch_bounds__(256) void ln_kernel(const float* __restrict__ x,
                                                 const float* __restrict__ g,
                                                 const float* __restrict__ b,
                                                 bf16_t* __restrict__ y) {
    __shared__ float red[4];
    long row = blockIdx.x;
    const float* xr = x + row * DIM;
    int tid = threadIdx.x;
    float4 v = *(const float4*)(xr + tid * 4);
    if (PRE) {
        float s  = block_sum(v.x + v.y + v.z + v.w, red);
        float mu = s * (1.0f / DIM);
        v.x -= mu; v.y -= mu; v.z -= mu; v.w -= mu;
        float ss = block_sum(v.x*v.x + v.y*v.y + v.z*v.z + v.w*v.w, red);
        float r  = 1.0f / sqrtf(ss * (1.0f / DIM) + 1e-6f);
        v.x *= r; v.y *= r; v.z *= r; v.w *= r;
    }
    float s  = block_sum(v.x + v.y + v.z + v.w, red);
    float mu = s * (1.0f / DIM);
    v.x -= mu; v.y -= mu; v.z -= mu; v.w -= mu;
    float ss = block_sum(v.x*v.x + v.y*v.y + v.z*v.z + v.w*v.w, red);
    float r  = 1.0f / sqrtf(ss * (1.0f / DIM) + 1e-5f);
    float4 gg = *(const float4*)(g + tid * 4);
    float4 bb = *(const float4*)(b + tid * 4);
    us4 o;
    o.x = f2bfu(v.x * r * gg.x + bb.x);
    o.y = f2bfu(v.y * r * gg.y + bb.y);
    o.z = f2bfu(v.z * r * gg.z + bb.z);
    o.w = f2bfu(v.w * r * gg.w + bb.w);
    *(us4*)(y + row * DIM + tid * 4) = o;
}

// ---------------- merged transpose+cvt: all 6 weight groups in one launch
// 128(K) x 64(N) tiles. LDS [128][64] fp32, XOR col-swizzle (write-phase
// conflict-free, read-phase 2-way=free). Global writes: 4 rows x 256 B per wave.
struct TxPack {
    const float* src[6];
    bf16_t*      dst[6];
    int K[6], N[6];
    int blk0[6];
};

__global__ __launch_bounds__(256) void tx128(TxPack p) {
    int bid = blockIdx.x;
    int s = 0;
    #pragma unroll
    for (int i = 1; i < 6; ++i) if (bid >= p.blk0[i]) s = i;
    int local = bid - p.blk0[s];
    int K = p.K[s], N = p.N[s];
    int ntn = N >> 6, ntk = K >> 7, tpg = ntn * ntk;
    int g  = local / tpg;
    int t_ = local - g * tpg;
    int kt = t_ / ntn, nt = t_ - kt * ntn;
    const float* src = p.src[s] + (long)g * K * N;
    bf16_t*      dst = p.dst[s] + (long)g * K * N;
    int k0 = kt * 128, n0 = nt * 64;

    __shared__ float t[128][64];
    int tid = threadIdx.x;
    {
        int rb = tid >> 4;             // 0..15
        int c  = (tid & 15) * 4;       // 0..60
        #pragma unroll
        for (int i = 0; i < 8; ++i) {
            int r = rb + i * 16;
            float4 v = *(const float4*)(src + (long)(k0 + r) * N + n0 + c);
            *(float4*)&t[r][c ^ (((r >> 3) & 15) << 2)] = v;
        }
    }
    __syncthreads();
    {
        int nb = tid >> 4;             // 0..15
        int kc = tid & 15;             // 16 chunks of 8 k-elems
        #pragma unroll
        for (int q = 0; q < 4; ++q) {
            int n = nb + q * 16;
            us8 o;
            #pragma unroll
            for (int j = 0; j < 8; ++j) {
                int r = kc * 8 + j;
                o[j] = f2bfu(t[r][n ^ (((r >> 3) & 15) << 2)]);
            }
            *(us8*)(dst + (long)(n0 + n) * K + k0 + kc * 8) = o;
        }
    }
}

// ---------------- 32x32x16 MFMA GEMM (transformer layers)
// A[M][K] bf16, BT[N][K] bf16, BK=64 (4 k-slices of 16), fragment-ordered LDS.
// EPI: 0 = none (bf16 out), 1 = +bias +resid (fp32 out), 2 = +bias gelu (bf16)
template<int BM, int BN, int WM, int WN, int EPI>
__global__ __launch_bounds__(256) void gemm32(
    const bf16_t* __restrict__ A, const bf16_t* __restrict__ BT,
    const float* __restrict__ bias, const float* __restrict__ resid,
    void* __restrict__ Cv,
    int M, int N, int K)
{
    constexpr int WAVES_N = BN / WN;
    constexpr int FM = WM / 32, FN = WN / 32;
    float*  Cf = (float*)Cv;
    bf16_t* Ch = (bf16_t*)Cv;

    __shared__ bf16_t As[BM * 64];
    __shared__ bf16_t Bs[BN * 64];

    int tid  = threadIdx.x;
    int wave = tid >> 6, lane = tid & 63;
    int wr = wave / WAVES_N, wc = wave % WAVES_N;
    int m0 = blockIdx.y * BM, n0 = blockIdx.x * BN;

    f32x16 acc[FM][FN];
    #pragma unroll
    for (int m = 0; m < FM; ++m)
        #pragma unroll
        for (int n = 0; n < FN; ++n)
            #pragma unroll
            for (int r = 0; r < 16; ++r)
                acc[m][n][r] = 0.f;

    long rsb = (long)K * 2;                  // row byte stride
    int  lr  = lane & 31;                    // fragment row within subtile
    int  lkb = (lane >> 5) * 16;             // 16B k-chunk within 32B row-span

    const char* Abase = (const char*)A + (long)(m0 + lr) * rsb + lkb;
    const char* Bbase = (const char*)BT + (long)(n0 + lr) * rsb + lkb;

    for (int k0 = 0; k0 < K; k0 += 64) {
        long kb = (long)k0 * 2;
        #pragma unroll
        for (int i = 0; i < BM / 32; ++i) {
            int b = i * 4 + wave;            // b = s*4 + kk
            gload_lds16(Abase + (long)(b >> 2) * 32 * rsb + (b & 3) * 32 + kb,
                        (char*)As + b * 1024);
        }
        #pragma unroll
        for (int i = 0; i < BN / 32; ++i) {
            int b = i * 4 + wave;
            gload_lds16(Bbase + (long)(b >> 2) * 32 * rsb + (b & 3) * 32 + kb,
                        (char*)Bs + b * 1024);
        }
        __syncthreads();
        bf16x8 af[FM][4], bq[FN][4];
        #pragma unroll
        for (int m = 0; m < FM; ++m)
            #pragma unroll
            for (int kk = 0; kk < 4; ++kk)
                af[m][kk] = *(const bf16x8*)((const char*)As +
                            ((wr * FM + m) * 4 + kk) * 1024 + (lane << 4));
        #pragma unroll
        for (int n = 0; n < FN; ++n)
            #pragma unroll
            for (int kk = 0; kk < 4; ++kk)
                bq[n][kk] = *(const bf16x8*)((const char*)Bs +
                            ((wc * FN + n) * 4 + kk) * 1024 + (lane << 4));
        #pragma unroll
        for (int kk = 0; kk < 4; ++kk)
            #pragma unroll
            for (int m = 0; m < FM; ++m)
                #pragma unroll
                for (int n = 0; n < FN; ++n)
                    acc[m][n] = __builtin_amdgcn_mfma_f32_32x32x16_bf16(
                        af[m][kk], bq[n][kk], acc[m][n], 0, 0, 0);
        __syncthreads();
    }

    // C/D layout (m74/m101): col = lane&31, row = (reg&3) + 8*(reg>>2) + 4*(lane>>5)
    int rbase = 4 * (lane >> 5);
    #pragma unroll
    for (int m = 0; m < FM; ++m) {
        #pragma unroll
        for (int n = 0; n < FN; ++n) {
            int colI = n0 + wc * WN + n * 32 + (lane & 31);
            float bb = (EPI != 0) ? bias[colI] : 0.f;
            #pragma unroll
            for (int r = 0; r < 16; ++r) {
                int rowI = m0 + wr * WM + m * 32 + rbase + (r & 3) + 8 * (r >> 2);
                float v = acc[m][n][r] + bb;
                if (EPI == 2) v = 0.5f * v * (1.0f + erff(v * 0.70710678118654752f));
                long off = (long)rowI * N + colI;
                if (EPI == 1)      Cf[off] = v + resid[off];
                else               Ch[off] = (bf16_t)v;
            }
        }
    }
}

// ---------------- 16x16x32 MFMA GEMM (heads), fragment-ordered, BK=64
// EPI: 3 = +bias relu (bf16 out)
template<int BM, int BN, int WM, int WN, int EPI>
__global__ __launch_bounds__(256) void gemm_bt(
    const bf16_t* __restrict__ A, const bf16_t* __restrict__ BT,
    const float* __restrict__ bias, const float* __restrict__ resid,
    void* __restrict__ Cv,
    int M, int N, int K, long sA, long sB, long sbias, long sC)
{
    constexpr int WAVES_N = BN / WN;
    constexpr int FM = WM / 16, FN = WN / 16;
    long g = blockIdx.z;
    A  += g * sA;
    BT += g * sB;
    if (EPI != 0) bias += g * sbias;
    float*  Cf = (float*)Cv + g * sC;
    bf16_t* Ch = (bf16_t*)Cv + g * sC;

    __shared__ bf16_t As[BM * 64];
    __shared__ bf16_t Bs[BN * 64];

    int tid  = threadIdx.x;
    int wave = tid >> 6, lane = tid & 63;
    int wr = wave / WAVES_N, wc = wave % WAVES_N;
    int m0 = blockIdx.y * BM, n0 = blockIdx.x * BN;

    f32x4 acc[FM][FN];
    #pragma unroll
    for (int m = 0; m < FM; ++m)
        #pragma unroll
        for (int n = 0; n < FN; ++n)
            acc[m][n] = f32x4{0.f, 0.f, 0.f, 0.f};

    long rsb = (long)K * 2;
    int  lr  = lane & 15;
    int  lkb = (lane >> 4) * 16;

    const char* Abase = (const char*)A + (long)(m0 + lr) * rsb + lkb;
    const char* Bbase = (const char*)BT + (long)(n0 + lr) * rsb + lkb;

    for (int k0 = 0; k0 < K; k0 += 64) {
        long kb = (long)k0 * 2;
        #pragma unroll
        for (int i = 0; i < BM / 32; ++i) {
            int b = i * 4 + wave;
            gload_lds16(Abase + (long)(b >> 1) * 16 * rsb + (b & 1) * 64 + kb,
                        (char*)As + b * 1024);
        }
        #pragma unroll
        for (int i = 0; i < BN / 32; ++i) {
            int b = i * 4 + wave;
            gload_lds16(Bbase + (long)(b >> 1) * 16 * rsb + (b & 1) * 64 + kb,
                        (char*)Bs + b * 1024);
        }
        __syncthreads();
        bf16x8 af[FM][2], bq[FN][2];
        #pragma unroll
        for (int m = 0; m < FM; ++m)
            #pragma unroll
            for (int h = 0; h < 2; ++h)
                af[m][h] = *(const bf16x8*)((const char*)As +
                           ((wr * FM + m) * 2 + h) * 1024 + (lane << 4));
        #pragma unroll
        for (int n = 0; n < FN; ++n)
            #pragma unroll
            for (int h = 0; h < 2; ++h)
                bq[n][h] = *(const bf16x8*)((const char*)Bs +
                           ((wc * FN + n) * 2 + h) * 1024 + (lane << 4));
        #pragma unroll
        for (int h = 0; h < 2; ++h)
            #pragma unroll
            for (int m = 0; m < FM; ++m)
                #pragma unroll
                for (int n = 0; n < FN; ++n)
                    acc[m][n] = __builtin_amdgcn_mfma_f32_16x16x32_bf16(
                        af[m][h], bq[n][h], acc[m][n], 0, 0, 0);
        __syncthreads();
    }

    int lq = (lane >> 4) * 4;
    #pragma unroll
    for (int m = 0; m < FM; ++m) {
        #pragma unroll
        for (int n = 0; n < FN; ++n) {
            int colI = n0 + wc * WN + n * 16 + lr;
            #pragma unroll
            for (int j = 0; j < 4; ++j) {
                int rowI = m0 + wr * WM + m * 16 + lq + j;
                float v = acc[m][n][j];
                if (EPI != 0) v += bias[colI];
                if (EPI == 2) v = 0.5f * v * (1.0f + erff(v * 0.70710678118654752f));
                if (EPI == 3) v = fmaxf(v, 0.0f);
                long off = (long)rowI * N + colI;
                if (EPI == 1)      Cf[off] = v + resid[off];
                else               Ch[off] = (bf16_t)v;
            }
        }
    }
}

// ---------------- fused attention: one block per (batch, head). T=32, HD=64.
__global__ __launch_bounds__(256) void attn_kernel(const bf16_t* __restrict__ qkv,
                                                   bf16_t* __restrict__ o) {
    int bh = blockIdx.x;
    int b  = bh >> 4;
    int hh = bh & 15;
    __shared__ float qs[32][64];
    __shared__ float kt[64][33];
    __shared__ float vs[32][64];
    __shared__ float ps[32][33];
    const bf16_t* base = qkv + (long)b * SEQ * (3 * DIM) + hh * HDIM;
    int tid = threadIdx.x;

    {   // 256 threads cover 32 rows x 8 chunks of 8 elems
        int t = tid >> 3, c = (tid & 7) * 8;
        bf16x8 qv = *(const bf16x8*)(base + (long)t * 3 * DIM + c);
        bf16x8 kv = *(const bf16x8*)(base + (long)t * 3 * DIM + DIM + c);
        bf16x8 vv = *(const bf16x8*)(base + (long)t * 3 * DIM + 2 * DIM + c);
        #pragma unroll
        for (int j = 0; j < 8; ++j) {
            qs[t][c + j] = (float)qv[j];
            kt[c + j][t] = (float)kv[j];
            vs[t][c + j] = (float)vv[j];
        }
    }
    __syncthreads();

    for (int i = tid; i < 1024; i += 256) {
        int r = i >> 5, c = i & 31;
        float acc = 0.f;
        #pragma unroll
        for (int d = 0; d < 64; ++d) acc = fmaf(qs[r][d], kt[d][c], acc);
        ps[r][c] = acc * 0.125f;
    }
    __syncthreads();

    if (tid < 32) {
        float mx = -1e30f;
        for (int c = 0; c < 32; ++c) mx = fmaxf(mx, ps[tid][c]);
        float sum = 0.f;
        for (int c = 0; c < 32; ++c) { float e = expf(ps[tid][c] - mx); ps[tid][c] = e; sum += e; }
        float inv = 1.f / sum;
        for (int c = 0; c < 32; ++c) ps[tid][c] *= inv;
    }
    __syncthreads();

    for (int i = tid; i < 2048; i += 256) {
        int r = i >> 6, d = i & 63;
        float acc = 0.f;
        #pragma unroll
        for (int c = 0; c < 32; ++c) acc = fmaf(ps[r][c], vs[c][d], acc);
        o[(long)b * SEQ * DIM + (long)r * DIM + hh * HDIM + d] = (bf16_t)acc;
    }
}

// ---------------- x_comb -> bf16
__global__ void comb_kernel(const float* __restrict__ h, bf16_t* __restrict__ xc) {
    int i = blockIdx.x * 256 + threadIdx.x;
    int b = i >> 11;
    int c = i & 2047;
    xc[i] = (bf16_t)h[(long)b * (SEQ * DIM) + c];
}

// ---------------- head layer 3: one wave per (n, b), dot-512
__global__ __launch_bounds__(256) void head3_kernel(const bf16_t* __restrict__ h2,
                                                    const float* __restrict__ w3,
                                                    const float* __restrict__ b3,
                                                    float* __restrict__ out) {
    int gid  = blockIdx.x * 256 + threadIdx.x;
    int wave = gid >> 6;
    int lane = gid & 63;
    if (wave >= NHEAD_OUT * BATCH) return;
    int n = wave >> 6;
    int b = wave & 63;
    const bf16_t* a = h2 + ((long)n * BATCH + b) * IDH;
    const float*  w = w3 + (long)n * IDH;
    float acc = 0.f;
    #pragma unroll
    for (int i = lane; i < IDH; i += 64) acc = fmaf((float)a[i], w[i], acc);
    #pragma unroll
    for (int off = 32; off > 0; off >>= 1) acc += __shfl_down(acc, off);
    if (lane == 0) out[b * NHEAD_OUT + n] = acc + b3[n];
}

extern "C" void kernel_launch(void* const* d_in, const int* in_sizes, int n_in,
                              void* d_out, int out_size, void* d_ws, size_t ws_size,
                              hipStream_t stream) {
    const float* x      = (const float*)d_in[0];
    const float* qkv_w  = (const float*)d_in[1];
    const float* out_w  = (const float*)d_in[2];
    const float* out_b  = (const float*)d_in[3];
    const float* attn_g = (const float*)d_in[4];
    const float* attn_b = (const float*)d_in[5];
    const float* ff_g   = (const float*)d_in[6];
    const float* ff_b   = (const float*)d_in[7];
    const float* ff_w1  = (const float*)d_in[8];
    const float* ff_b1  = (const float*)d_in[9];
    const float* ff_w2  = (const float*)d_in[10];
    const float* ff_b2  = (const float*)d_in[11];
    const float* hw1    = (const float*)d_in[12];
    const float* hb1    = (const float*)d_in[13];
    const float* hw2    = (const float*)d_in[14];
    const float* hb2    = (const float*)d_in[15];
    const float* hw3    = (const float*)d_in[16];
    const float* hb3    = (const float*)d_in[17];
    float* out = (float*)d_out;

    char* p = (char*)d_ws;
    float*  h     = (float*)p;            p += (long)TOK * DIM * 4;
    bf16_t* qkvb  = (bf16_t*)p;           p += (long)TOK * 3 * DIM * 2;
    bf16_t* y     = (bf16_t*)p;           p += (long)TOK * DIM * 2;
    bf16_t* ob    = (bf16_t*)p;           p += (long)TOK * DIM * 2;
    bf16_t* ffb   = (bf16_t*)p;           p += (long)TOK * FFD * 2;
    bf16_t* xc    = (bf16_t*)p;           p += (long)BATCH * 2 * DIM * 2;
    bf16_t* h1    = (bf16_t*)p;           p += (long)NHEAD_OUT * BATCH * IDH * 2;
    bf16_t* h2    = (bf16_t*)p;           p += (long)NHEAD_OUT * BATCH * IDH * 2;
    bf16_t* qkvwt = (bf16_t*)p;           p += (long)LAYERS * DIM * 3 * DIM * 2;
    bf16_t* outwt = (bf16_t*)p;           p += (long)LAYERS * DIM * DIM * 2;
    bf16_t* ff1t  = (bf16_t*)p;           p += (long)LAYERS * DIM * FFD * 2;
    bf16_t* ff2t  = (bf16_t*)p;           p += (long)LAYERS * FFD * DIM * 2;
    bf16_t* hw1t  = (bf16_t*)p;           p += (long)NHEAD_OUT * 2 * DIM * IDH * 2;
    bf16_t* hw2t  = (bf16_t*)p;           p += (long)NHEAD_OUT * IDH * IDH * 2;

    // ---- merged weight transpose+convert (single launch) ----
    TxPack tp;
    tp.src[0] = qkv_w; tp.dst[0] = qkvwt; tp.K[0] = DIM;     tp.N[0] = 3 * DIM;
    tp.src[1] = out_w; tp.dst[1] = outwt; tp.K[1] = DIM;     tp.N[1] = DIM;
    tp.src[2] = ff_w1; tp.dst[2] = ff1t;  tp.K[2] = DIM;     tp.N[2] = FFD;
    tp.src[3] = ff_w2; tp.dst[3] = ff2t;  tp.K[3] = FFD;     tp.N[3] = DIM;
    tp.src[4] = hw1;   tp.dst[4] = hw1t;  tp.K[4] = 2 * DIM; tp.N[4] = IDH;
    tp.src[5] = hw2;   tp.dst[5] = hw2t;  tp.K[5] = IDH;     tp.N[5] = IDH;
    int G[6] = {LAYERS, LAYERS, LAYERS, LAYERS, NHEAD_OUT, NHEAD_OUT};
    int nblk = 0;
    for (int i = 0; i < 6; ++i) {
        tp.blk0[i] = nblk;
        nblk += G[i] * (tp.K[i] >> 7) * (tp.N[i] >> 6);
    }
    tx128<<<nblk, 256, 0, stream>>>(tp);

    hipMemcpyAsync(h, x, (size_t)TOK * DIM * sizeof(float),
                   hipMemcpyDeviceToDevice, stream);

    for (int l = 0; l < LAYERS; ++l) {
        ln_kernel<true><<<TOK, 256, 0, stream>>>(h, attn_g + l * DIM, attn_b + l * DIM, y);
        // qkv: M=2048, N=3072 -> 64x128 tiles, 768 blocks
        gemm32<64, 128, 32, 64, 0><<<dim3(3 * DIM / 128, TOK / 64), 256, 0, stream>>>(
            y, qkvwt + (long)l * DIM * 3 * DIM, nullptr, nullptr, qkvb,
            TOK, 3 * DIM, DIM);
        attn_kernel<<<BATCH * NH, 256, 0, stream>>>(qkvb, ob);
        // out-proj: 64x64 tiles, 512 blocks
        gemm32<64, 64, 32, 32, 1><<<dim3(DIM / 64, TOK / 64), 256, 0, stream>>>(
            ob, outwt + (long)l * DIM * DIM, out_b + l * DIM, h, h,
            TOK, DIM, DIM);
        ln_kernel<false><<<TOK, 256, 0, stream>>>(h, ff_g + l * DIM, ff_b + l * DIM, y);
        // ff1: 64x128 tiles, 512 blocks
        gemm32<64, 128, 32, 64, 2><<<dim3(FFD / 128, TOK / 64), 256, 0, stream>>>(
            y, ff1t + (long)l * DIM * FFD, ff_b1 + l * FFD, nullptr, ffb,
            TOK, FFD, DIM);
        // ff2: 64x64 tiles, 512 blocks
        gemm32<64, 64, 32, 32, 1><<<dim3(DIM / 64, TOK / 64), 256, 0, stream>>>(
            ffb, ff2t + (long)l * FFD * DIM, ff_b2 + l * DIM, h, h,
            TOK, DIM, FFD);
    }

    comb_kernel<<<(BATCH * 2 * DIM) / 256, 256, 0, stream>>>(h, xc);

    gemm_bt<64, 64, 32, 32, 3><<<dim3(IDH / 64, 1, NHEAD_OUT), 256, 0, stream>>>(
        xc, hw1t, hb1, nullptr, h1,
        BATCH, IDH, 2 * DIM,
        0, (long)2 * DIM * IDH, IDH, (long)BATCH * IDH);
    gemm_bt<64, 64, 32, 32, 3><<<dim3(IDH / 64, 1, NHEAD_OUT), 256, 0, stream>>>(
        h1, hw2t, hb2, nullptr, h2,
        BATCH, IDH, IDH,
        (long)BATCH * IDH, (long)IDH * IDH, IDH, (long)BATCH * IDH);
    head3_kernel<<<(NHEAD_OUT * BATCH * 64) / 256, 256, 0, stream>>>(h2, hw3, hb3, out);
}

// Round 7
// 659.804 us; speedup vs baseline: 1.3087x; 1.0816x over previous
//
#include <hip/hip_runtime.h>
#include <math.h>

static constexpr int BATCH = 64;
static constexpr int SEQ   = 32;
static constexpr int TOK   = BATCH * SEQ;   // 2048
static constexpr int DIM   = 1024;
static constexpr int NH    = 16;
static constexpr int HDIM  = 64;
static constexpr int FFD   = 2048;
static constexpr int LAYERS= 4;
static constexpr int NHEAD_OUT = 26;
static constexpr int IDH   = 512;

typedef __bf16 bf16_t;
typedef __bf16 bf16x8 __attribute__((ext_vector_type(8)));
typedef float  f32x4  __attribute__((ext_vector_type(4)));
typedef float  f32x16 __attribute__((ext_vector_type(16)));
typedef unsigned short us4 __attribute__((ext_vector_type(4)));
typedef unsigned short us8 __attribute__((ext_vector_type(8)));

__device__ __forceinline__ unsigned short f2bfu(float f) {
    return __builtin_bit_cast(unsigned short, (bf16_t)f);
}

__device__ __forceinline__ void gload_lds16(const void* gp, void* lp) {
    __builtin_amdgcn_global_load_lds(
        (const __attribute__((address_space(1))) unsigned int*)gp,
        (__attribute__((address_space(3))) unsigned int*)lp,
        16, 0, 0);
}

// ---------------- block-wide sum (256 threads = 4 waves) ----------------
__device__ __forceinline__ float block_sum(float v, float* red) {
    #pragma unroll
    for (int off = 32; off > 0; off >>= 1) v += __shfl_down(v, off);
    int lane = threadIdx.x & 63;
    int w    = threadIdx.x >> 6;
    if (lane == 0) red[w] = v;
    __syncthreads();
    float t = red[0] + red[1] + red[2] + red[3];
    __syncthreads();
    return t;
}

// ---------------- LayerNorm -> bf16 output
template<bool PRE>
__global__ __launch_bounds__(256) void ln_kernel(const float* __restrict__ x,
                                                 const float* __restrict__ g,
                                                 const float* __restrict__ b,
                                                 bf16_t* __restrict__ y) {
    __shared__ float red[4];
    long row = blockIdx.x;
    const float* xr = x + row * DIM;
    int tid = threadIdx.x;
    float4 v = *(const float4*)(xr + tid * 4);
    if (PRE) {
        float s  = block_sum(v.x + v.y + v.z + v.w, red);
        float mu = s * (1.0f / DIM);
        v.x -= mu; v.y -= mu; v.z -= mu; v.w -= mu;
        float ss = block_sum(v.x*v.x + v.y*v.y + v.z*v.z + v.w*v.w, red);
        float r  = 1.0f / sqrtf(ss * (1.0f / DIM) + 1e-6f);
        v.x *= r; v.y *= r; v.z *= r; v.w *= r;
    }
    float s  = block_sum(v.x + v.y + v.z + v.w, red);
    float mu = s * (1.0f / DIM);
    v.x -= mu; v.y -= mu; v.z -= mu; v.w -= mu;
    float ss = block_sum(v.x*v.x + v.y*v.y + v.z*v.z + v.w*v.w, red);
    float r  = 1.0f / sqrtf(ss * (1.0f / DIM) + 1e-5f);
    float4 gg = *(const float4*)(g + tid * 4);
    float4 bb = *(const float4*)(b + tid * 4);
    us4 o;
    o.x = f2bfu(v.x * r * gg.x + bb.x);
    o.y = f2bfu(v.y * r * gg.y + bb.y);
    o.z = f2bfu(v.z * r * gg.z + bb.z);
    o.w = f2bfu(v.w * r * gg.w + bb.w);
    *(us4*)(y + row * DIM + tid * 4) = o;
}

// ---------------- merged transpose+cvt: transformer weights only (4 groups)
struct TxPack {
    const float* src[4];
    bf16_t*      dst[4];
    int K[4], N[4];
    int blk0[4];
};

__global__ __launch_bounds__(256) void tx64(TxPack p) {
    int bid = blockIdx.x;
    int s = 0;
    #pragma unroll
    for (int i = 1; i < 4; ++i) if (bid >= p.blk0[i]) s = i;
    int local = bid - p.blk0[s];
    int K = p.K[s], N = p.N[s];
    int ntn = N >> 6, ntk = K >> 6, tpg = ntn * ntk;
    int g  = local / tpg;
    int t_ = local - g * tpg;
    int kt = t_ / ntn, nt = t_ - kt * ntn;
    const float* src = p.src[s] + (long)g * K * N;
    bf16_t*      dst = p.dst[s] + (long)g * K * N;
    int k0 = kt * 64, n0 = nt * 64;

    __shared__ float t[64][68];
    int tid = threadIdx.x;
    int kr = tid >> 4;             // 0..15
    int nc = (tid & 15) * 4;       // 0..60
    #pragma unroll
    for (int i = 0; i < 4; ++i) {
        int k = kr + i * 16;
        float4 v = *(const float4*)(src + (long)(k0 + k) * N + n0 + nc);
        t[k][nc] = v.x; t[k][nc+1] = v.y; t[k][nc+2] = v.z; t[k][nc+3] = v.w;
    }
    __syncthreads();
    int kc = tid & 7;              // k-chunk (8 elems)
    int nr = tid >> 3;             // 0..31
    #pragma unroll
    for (int h = 0; h < 2; ++h) {
        int n = nr + h * 32;
        us8 o;
        #pragma unroll
        for (int j = 0; j < 8; ++j)
            o[j] = f2bfu(t[kc * 8 + j][n]);
        *(us8*)(dst + (long)(n0 + n) * K + k0 + kc * 8) = o;
    }
}

// ---------------- 32x32x16 MFMA GEMM (transformer layers)
// BK=64, double-buffered LDS, counted vmcnt + raw s_barrier (T3+T4),
// fragment-ordered LDS (linear dest, pre-permuted global src).
// EPI: 0 = none (bf16 out), 1 = +bias +resid (fp32 out), 2 = +bias gelu (bf16)
template<int BM, int BN, int WM, int WN, int EPI>
__global__ __launch_bounds__(256) void gemm32(
    const bf16_t* __restrict__ A, const bf16_t* __restrict__ BT,
    const float* __restrict__ bias, const float* __restrict__ resid,
    void* __restrict__ Cv,
    int M, int N, int K)
{
    constexpr int WAVES_N = BN / WN;
    constexpr int FM = WM / 32, FN = WN / 32;
    constexpr int NSTG = BM / 32 + BN / 32;
    float*  Cf = (float*)Cv;
    bf16_t* Ch = (bf16_t*)Cv;

    __shared__ bf16_t As[2][BM * 64];
    __shared__ bf16_t Bs[2][BN * 64];

    int tid  = threadIdx.x;
    int wave = tid >> 6, lane = tid & 63;
    int wr = wave / WAVES_N, wc = wave % WAVES_N;
    int m0 = blockIdx.y * BM, n0 = blockIdx.x * BN;

    f32x16 acc[FM][FN];
    #pragma unroll
    for (int m = 0; m < FM; ++m)
        #pragma unroll
        for (int n = 0; n < FN; ++n)
            #pragma unroll
            for (int r = 0; r < 16; ++r)
                acc[m][n][r] = 0.f;

    long rsb = (long)K * 2;                  // row byte stride
    int  lr  = lane & 31;                    // fragment row within subtile
    int  lkb = (lane >> 5) * 16;             // 16B k-chunk within 32B row-span

    const char* Abase = (const char*)A + (long)(m0 + lr) * rsb + lkb;
    const char* Bbase = (const char*)BT + (long)(n0 + lr) * rsb + lkb;

    auto stage = [&](int c, int t) {
        long kb = (long)t * 128;             // t*64 k * 2B
        #pragma unroll
        for (int i = 0; i < BM / 32; ++i) {
            int b = i * 4 + wave;
            gload_lds16(Abase + (long)(b >> 2) * 32 * rsb + (b & 3) * 32 + kb,
                        (char*)&As[c][0] + b * 1024);
        }
        #pragma unroll
        for (int i = 0; i < BN / 32; ++i) {
            int b = i * 4 + wave;
            gload_lds16(Bbase + (long)(b >> 2) * 32 * rsb + (b & 3) * 32 + kb,
                        (char*)&Bs[c][0] + b * 1024);
        }
    };

    int nt = K >> 6;
    stage(0, 0);
    int cur = 0;
    for (int t = 0; t < nt; ++t) {
        if (t + 1 < nt) {
            stage(cur ^ 1, t + 1);
            asm volatile("s_waitcnt vmcnt(%c0)" :: "i"(NSTG) : "memory");
        } else {
            asm volatile("s_waitcnt vmcnt(0)" ::: "memory");
        }
        __builtin_amdgcn_s_barrier();
        asm volatile("" ::: "memory");
        bf16x8 af[FM][4], bq[FN][4];
        #pragma unroll
        for (int m = 0; m < FM; ++m)
            #pragma unroll
            for (int kk = 0; kk < 4; ++kk)
                af[m][kk] = *(const bf16x8*)((const char*)&As[cur][0] +
                            ((wr * FM + m) * 4 + kk) * 1024 + (lane << 4));
        #pragma unroll
        for (int n = 0; n < FN; ++n)
            #pragma unroll
            for (int kk = 0; kk < 4; ++kk)
                bq[n][kk] = *(const bf16x8*)((const char*)&Bs[cur][0] +
                            ((wc * FN + n) * 4 + kk) * 1024 + (lane << 4));
        #pragma unroll
        for (int kk = 0; kk < 4; ++kk)
            #pragma unroll
            for (int m = 0; m < FM; ++m)
                #pragma unroll
                for (int n = 0; n < FN; ++n)
                    acc[m][n] = __builtin_amdgcn_mfma_f32_32x32x16_bf16(
                        af[m][kk], bq[n][kk], acc[m][n], 0, 0, 0);
        asm volatile("" ::: "memory");
        __builtin_amdgcn_s_barrier();
        cur ^= 1;
    }

    // C/D layout: col = lane&31, row = (reg&3) + 8*(reg>>2) + 4*(lane>>5)
    int rbase = 4 * (lane >> 5);
    #pragma unroll
    for (int m = 0; m < FM; ++m) {
        #pragma unroll
        for (int n = 0; n < FN; ++n) {
            int colI = n0 + wc * WN + n * 32 + (lane & 31);
            float bb = (EPI != 0) ? bias[colI] : 0.f;
            #pragma unroll
            for (int r = 0; r < 16; ++r) {
                int rowI = m0 + wr * WM + m * 32 + rbase + (r & 3) + 8 * (r >> 2);
                float v = acc[m][n][r] + bb;
                if (EPI == 2) v = 0.5f * v * (1.0f + erff(v * 0.70710678118654752f));
                long off = (long)rowI * N + colI;
                if (EPI == 1)      Cf[off] = v + resid[off];
                else               Ch[off] = (bf16_t)v;
            }
        }
    }
}

// ---------------- head GEMM: A bf16 [M][K] (fragment-ordered), B fp32 NATIVE [K][N]
// 64x64 tile, 4 waves (2x2 of 32x32), 16x16x32 MFMA, relu epilogue, bf16 out.
// Double-buffered, counted vmcnt + raw barriers. M == 64.
__global__ __launch_bounds__(256) void gemm_hd(
    const bf16_t* __restrict__ A, const float* __restrict__ Bw,
    const float* __restrict__ bias, bf16_t* __restrict__ C,
    int N, int K, long sA, long sB, long sbias, long sC)
{
    long g = blockIdx.z;
    A += g * sA;
    const float* Bp = Bw + g * sB;
    bias += g * sbias;
    bf16_t* Cp = C + g * sC;

    __shared__ bf16_t As[2][64 * 64];
    __shared__ float  Bf[2][64 * 64];

    int tid = threadIdx.x, wave = tid >> 6, lane = tid & 63;
    int wr = wave >> 1, wc = wave & 1;
    int n0 = blockIdx.x * 64;

    f32x4 acc[2][2];
    #pragma unroll
    for (int m = 0; m < 2; ++m)
        #pragma unroll
        for (int n = 0; n < 2; ++n)
            acc[m][n] = f32x4{0.f, 0.f, 0.f, 0.f};

    long rsb = (long)K * 2;
    int  lr  = lane & 15;
    int  lkb = (lane >> 4) * 16;
    const char* Abase = (const char*)A + (long)lr * rsb + lkb;   // m0 = 0

    auto stage = [&](int c, int t) {
        long kb = (long)t * 128;
        #pragma unroll
        for (int i = 0; i < 2; ++i) {            // A: 64x64 bf16, fragment-ordered
            int b = i * 4 + wave;
            gload_lds16(Abase + (long)(b >> 1) * 16 * rsb + (b & 1) * 64 + kb,
                        (char*)&As[c][0] + b * 1024);
        }
        #pragma unroll
        for (int i = 0; i < 4; ++i) {            // B: 64k x 64n fp32 row-major
            int ch = i * 4 + wave;
            int row = ch * 4 + (lane >> 4);
            gload_lds16((const char*)Bp + ((long)(t * 64 + row) * N + n0) * 4 + (lane & 15) * 16,
                        (char*)&Bf[c][0] + ch * 1024);
        }
    };

    int nt = K >> 6;
    stage(0, 0);
    int cur = 0;
    for (int t = 0; t < nt; ++t) {
        if (t + 1 < nt) {
            stage(cur ^ 1, t + 1);
            asm volatile("s_waitcnt vmcnt(6)" ::: "memory");
        } else {
            asm volatile("s_waitcnt vmcnt(0)" ::: "memory");
        }
        __builtin_amdgcn_s_barrier();
        asm volatile("" ::: "memory");
        bf16x8 af[2][2], bq[2][2];
        #pragma unroll
        for (int m = 0; m < 2; ++m)
            #pragma unroll
            for (int h = 0; h < 2; ++h)
                af[m][h] = *(const bf16x8*)((const char*)&As[cur][0] +
                           ((wr * 2 + m) * 2 + h) * 1024 + (lane << 4));
        #pragma unroll
        for (int n = 0; n < 2; ++n) {
            int nl = wc * 32 + n * 16 + lr;
            #pragma unroll
            for (int h = 0; h < 2; ++h) {
                #pragma unroll
                for (int j = 0; j < 8; ++j) {
                    float v = Bf[cur][(h * 32 + (lane >> 4) * 8 + j) * 64 + nl];
                    bq[n][h][j] = (bf16_t)v;
                }
            }
        }
        #pragma unroll
        for (int h = 0; h < 2; ++h)
            #pragma unroll
            for (int m = 0; m < 2; ++m)
                #pragma unroll
                for (int n = 0; n < 2; ++n)
                    acc[m][n] = __builtin_amdgcn_mfma_f32_16x16x32_bf16(
                        af[m][h], bq[n][h], acc[m][n], 0, 0, 0);
        asm volatile("" ::: "memory");
        __builtin_amdgcn_s_barrier();
        cur ^= 1;
    }

    int lq = (lane >> 4) * 4;
    #pragma unroll
    for (int m = 0; m < 2; ++m) {
        #pragma unroll
        for (int n = 0; n < 2; ++n) {
            int colI = n0 + wc * 32 + n * 16 + lr;
            float bb = bias[colI];
            #pragma unroll
            for (int j = 0; j < 4; ++j) {
                int rowI = wr * 32 + m * 16 + lq + j;
                float v = fmaxf(acc[m][n][j] + bb, 0.0f);
                Cp[(long)rowI * N + colI] = (bf16_t)v;
            }
        }
    }
}

// ---------------- fused attention: one block per (batch, head). T=32, HD=64.
__global__ __launch_bounds__(256) void attn_kernel(const bf16_t* __restrict__ qkv,
                                                   bf16_t* __restrict__ o) {
    int bh = blockIdx.x;
    int b  = bh >> 4;
    int hh = bh & 15;
    __shared__ float qs[32][64];
    __shared__ float kt[64][33];
    __shared__ float vs[32][64];
    __shared__ float ps[32][33];
    const bf16_t* base = qkv + (long)b * SEQ * (3 * DIM) + hh * HDIM;
    int tid = threadIdx.x;

    {
        int t = tid >> 3, c = (tid & 7) * 8;
        bf16x8 qv = *(const bf16x8*)(base + (long)t * 3 * DIM + c);
        bf16x8 kv = *(const bf16x8*)(base + (long)t * 3 * DIM + DIM + c);
        bf16x8 vv = *(const bf16x8*)(base + (long)t * 3 * DIM + 2 * DIM + c);
        #pragma unroll
        for (int j = 0; j < 8; ++j) {
            qs[t][c + j] = (float)qv[j];
            kt[c + j][t] = (float)kv[j];
            vs[t][c + j] = (float)vv[j];
        }
    }
    __syncthreads();

    for (int i = tid; i < 1024; i += 256) {
        int r = i >> 5, c = i & 31;
        float acc = 0.f;
        #pragma unroll
        for (int d = 0; d < 64; ++d) acc = fmaf(qs[r][d], kt[d][c], acc);
        ps[r][c] = acc * 0.125f;
    }
    __syncthreads();

    if (tid < 32) {
        float mx = -1e30f;
        for (int c = 0; c < 32; ++c) mx = fmaxf(mx, ps[tid][c]);
        float sum = 0.f;
        for (int c = 0; c < 32; ++c) { float e = expf(ps[tid][c] - mx); ps[tid][c] = e; sum += e; }
        float inv = 1.f / sum;
        for (int c = 0; c < 32; ++c) ps[tid][c] *= inv;
    }
    __syncthreads();

    for (int i = tid; i < 2048; i += 256) {
        int r = i >> 6, d = i & 63;
        float acc = 0.f;
        #pragma unroll
        for (int c = 0; c < 32; ++c) acc = fmaf(ps[r][c], vs[c][d], acc);
        o[(long)b * SEQ * DIM + (long)r * DIM + hh * HDIM + d] = (bf16_t)acc;
    }
}

// ---------------- x_comb -> bf16
__global__ void comb_kernel(const float* __restrict__ h, bf16_t* __restrict__ xc) {
    int i = blockIdx.x * 256 + threadIdx.x;
    int b = i >> 11;
    int c = i & 2047;
    xc[i] = (bf16_t)h[(long)b * (SEQ * DIM) + c];
}

// ---------------- head layer 3: one wave per (n, b), dot-512
__global__ __launch_bounds__(256) void head3_kernel(const bf16_t* __restrict__ h2,
                                                    const float* __restrict__ w3,
                                                    const float* __restrict__ b3,
                                                    float* __restrict__ out) {
    int gid  = blockIdx.x * 256 + threadIdx.x;
    int wave = gid >> 6;
    int lane = gid & 63;
    if (wave >= NHEAD_OUT * BATCH) return;
    int n = wave >> 6;
    int b = wave & 63;
    const bf16_t* a = h2 + ((long)n * BATCH + b) * IDH;
    const float*  w = w3 + (long)n * IDH;
    float acc = 0.f;
    #pragma unroll
    for (int i = lane; i < IDH; i += 64) acc = fmaf((float)a[i], w[i], acc);
    #pragma unroll
    for (int off = 32; off > 0; off >>= 1) acc += __shfl_down(acc, off);
    if (lane == 0) out[b * NHEAD_OUT + n] = acc + b3[n];
}

extern "C" void kernel_launch(void* const* d_in, const int* in_sizes, int n_in,
                              void* d_out, int out_size, void* d_ws, size_t ws_size,
                              hipStream_t stream) {
    const float* x      = (const float*)d_in[0];
    const float* qkv_w  = (const float*)d_in[1];
    const float* out_w  = (const float*)d_in[2];
    const float* out_b  = (const float*)d_in[3];
    const float* attn_g = (const float*)d_in[4];
    const float* attn_b = (const float*)d_in[5];
    const float* ff_g   = (const float*)d_in[6];
    const float* ff_b   = (const float*)d_in[7];
    const float* ff_w1  = (const float*)d_in[8];
    const float* ff_b1  = (const float*)d_in[9];
    const float* ff_w2  = (const float*)d_in[10];
    const float* ff_b2  = (const float*)d_in[11];
    const float* hw1    = (const float*)d_in[12];
    const float* hb1    = (const float*)d_in[13];
    const float* hw2    = (const float*)d_in[14];
    const float* hb2    = (const float*)d_in[15];
    const float* hw3    = (const float*)d_in[16];
    const float* hb3    = (const float*)d_in[17];
    float* out = (float*)d_out;

    char* p = (char*)d_ws;
    float*  h     = (float*)p;            p += (long)TOK * DIM * 4;
    bf16_t* qkvb  = (bf16_t*)p;           p += (long)TOK * 3 * DIM * 2;
    bf16_t* y     = (bf16_t*)p;           p += (long)TOK * DIM * 2;
    bf16_t* ob    = (bf16_t*)p;           p += (long)TOK * DIM * 2;
    bf16_t* ffb   = (bf16_t*)p;           p += (long)TOK * FFD * 2;
    bf16_t* xc    = (bf16_t*)p;           p += (long)BATCH * 2 * DIM * 2;
    bf16_t* h1    = (bf16_t*)p;           p += (long)NHEAD_OUT * BATCH * IDH * 2;
    bf16_t* h2    = (bf16_t*)p;           p += (long)NHEAD_OUT * BATCH * IDH * 2;
    bf16_t* qkvwt = (bf16_t*)p;           p += (long)LAYERS * DIM * 3 * DIM * 2;
    bf16_t* outwt = (bf16_t*)p;           p += (long)LAYERS * DIM * DIM * 2;
    bf16_t* ff1t  = (bf16_t*)p;           p += (long)LAYERS * DIM * FFD * 2;
    bf16_t* ff2t  = (bf16_t*)p;           p += (long)LAYERS * FFD * DIM * 2;

    // ---- transformer weight transpose+convert (heads excluded) ----
    TxPack tp;
    tp.src[0] = qkv_w; tp.dst[0] = qkvwt; tp.K[0] = DIM; tp.N[0] = 3 * DIM;
    tp.src[1] = out_w; tp.dst[1] = outwt; tp.K[1] = DIM; tp.N[1] = DIM;
    tp.src[2] = ff_w1; tp.dst[2] = ff1t;  tp.K[2] = DIM; tp.N[2] = FFD;
    tp.src[3] = ff_w2; tp.dst[3] = ff2t;  tp.K[3] = FFD; tp.N[3] = DIM;
    int nblk = 0;
    for (int i = 0; i < 4; ++i) {
        tp.blk0[i] = nblk;
        nblk += LAYERS * (tp.K[i] >> 6) * (tp.N[i] >> 6);
    }
    tx64<<<nblk, 256, 0, stream>>>(tp);

    hipMemcpyAsync(h, x, (size_t)TOK * DIM * sizeof(float),
                   hipMemcpyDeviceToDevice, stream);

    for (int l = 0; l < LAYERS; ++l) {
        ln_kernel<true><<<TOK, 256, 0, stream>>>(h, attn_g + l * DIM, attn_b + l * DIM, y);
        gemm32<64, 128, 32, 64, 0><<<dim3(3 * DIM / 128, TOK / 64), 256, 0, stream>>>(
            y, qkvwt + (long)l * DIM * 3 * DIM, nullptr, nullptr, qkvb,
            TOK, 3 * DIM, DIM);
        attn_kernel<<<BATCH * NH, 256, 0, stream>>>(qkvb, ob);
        gemm32<64, 64, 32, 32, 1><<<dim3(DIM / 64, TOK / 64), 256, 0, stream>>>(
            ob, outwt + (long)l * DIM * DIM, out_b + l * DIM, h, h,
            TOK, DIM, DIM);
        ln_kernel<false><<<TOK, 256, 0, stream>>>(h, ff_g + l * DIM, ff_b + l * DIM, y);
        gemm32<64, 128, 32, 64, 2><<<dim3(FFD / 128, TOK / 64), 256, 0, stream>>>(
            y, ff1t + (long)l * DIM * FFD, ff_b1 + l * FFD, nullptr, ffb,
            TOK, FFD, DIM);
        gemm32<64, 64, 32, 32, 1><<<dim3(DIM / 64, TOK / 64), 256, 0, stream>>>(
            ffb, ff2t + (long)l * FFD * DIM, ff_b2 + l * DIM, h, h,
            TOK, DIM, FFD);
    }

    comb_kernel<<<(BATCH * 2 * DIM) / 256, 256, 0, stream>>>(h, xc);

    // heads: fp32 weights read natively, no transpose pass
    gemm_hd<<<dim3(IDH / 64, 1, NHEAD_OUT), 256, 0, stream>>>(
        xc, hw1, hb1, h1,
        IDH, 2 * DIM, 0, (long)2 * DIM * IDH, IDH, (long)BATCH * IDH);
    gemm_hd<<<dim3(IDH / 64, 1, NHEAD_OUT), 256, 0, stream>>>(
        h1, hw2, hb2, h2,
        IDH, IDH, (long)BATCH * IDH, (long)IDH * IDH, IDH, (long)BATCH * IDH);
    head3_kernel<<<(NHEAD_OUT * BATCH * 64) / 256, 256, 0, stream>>>(h2, hw3, hb3, out);
}

// Round 8
// 654.398 us; speedup vs baseline: 1.3195x; 1.0083x over previous
//
#include <hip/hip_runtime.h>
#include <math.h>

static constexpr int BATCH = 64;
static constexpr int SEQ   = 32;
static constexpr int TOK   = BATCH * SEQ;   // 2048
static constexpr int DIM   = 1024;
static constexpr int NH    = 16;
static constexpr int HDIM  = 64;
static constexpr int FFD   = 2048;
static constexpr int LAYERS= 4;
static constexpr int NHEAD_OUT = 26;
static constexpr int IDH   = 512;

typedef __bf16 bf16_t;
typedef __bf16 bf16x8 __attribute__((ext_vector_type(8)));
typedef float  f32x4  __attribute__((ext_vector_type(4)));
typedef float  f32x16 __attribute__((ext_vector_type(16)));
typedef unsigned short us4 __attribute__((ext_vector_type(4)));
typedef unsigned short us8 __attribute__((ext_vector_type(8)));

__device__ __forceinline__ unsigned short f2bfu(float f) {
    return __builtin_bit_cast(unsigned short, (bf16_t)f);
}

__device__ __forceinline__ void gload_lds16(const void* gp, void* lp) {
    __builtin_amdgcn_global_load_lds(
        (const __attribute__((address_space(1))) unsigned int*)gp,
        (__attribute__((address_space(3))) unsigned int*)lp,
        16, 0, 0);
}

// ---------------- block-wide sum (256 threads = 4 waves) ----------------
__device__ __forceinline__ float block_sum(float v, float* red) {
    #pragma unroll
    for (int off = 32; off > 0; off >>= 1) v += __shfl_down(v, off);
    int lane = threadIdx.x & 63;
    int w    = threadIdx.x >> 6;
    if (lane == 0) red[w] = v;
    __syncthreads();
    float t = red[0] + red[1] + red[2] + red[3];
    __syncthreads();
    return t;
}

// ---------------- LayerNorm -> bf16 output
template<bool PRE>
__global__ __launch_bounds__(256) void ln_kernel(const float* __restrict__ x,
                                                 const float* __restrict__ g,
                                                 const float* __restrict__ b,
                                                 bf16_t* __restrict__ y) {
    __shared__ float red[4];
    long row = blockIdx.x;
    const float* xr = x + row * DIM;
    int tid = threadIdx.x;
    float4 v = *(const float4*)(xr + tid * 4);
    if (PRE) {
        float s  = block_sum(v.x + v.y + v.z + v.w, red);
        float mu = s * (1.0f / DIM);
        v.x -= mu; v.y -= mu; v.z -= mu; v.w -= mu;
        float ss = block_sum(v.x*v.x + v.y*v.y + v.z*v.z + v.w*v.w, red);
        float r  = 1.0f / sqrtf(ss * (1.0f / DIM) + 1e-6f);
        v.x *= r; v.y *= r; v.z *= r; v.w *= r;
    }
    float s  = block_sum(v.x + v.y + v.z + v.w, red);
    float mu = s * (1.0f / DIM);
    v.x -= mu; v.y -= mu; v.z -= mu; v.w -= mu;
    float ss = block_sum(v.x*v.x + v.y*v.y + v.z*v.z + v.w*v.w, red);
    float r  = 1.0f / sqrtf(ss * (1.0f / DIM) + 1e-5f);
    float4 gg = *(const float4*)(g + tid * 4);
    float4 bb = *(const float4*)(b + tid * 4);
    us4 o;
    o.x = f2bfu(v.x * r * gg.x + bb.x);
    o.y = f2bfu(v.y * r * gg.y + bb.y);
    o.z = f2bfu(v.z * r * gg.z + bb.z);
    o.w = f2bfu(v.w * r * gg.w + bb.w);
    *(us4*)(y + row * DIM + tid * 4) = o;
}

// ---------------- merged transpose+cvt: transformer weights only (4 groups)
// LDS [64][64] fp32 with granule-XOR swizzle (granule ^= k>>3):
// write phase quad-uniform, read phase 32 banks x 2 lanes (conflict-free).
struct TxPack {
    const float* src[4];
    bf16_t*      dst[4];
    int K[4], N[4];
    int blk0[4];
};

__global__ __launch_bounds__(256) void tx64(TxPack p) {
    int bid = blockIdx.x;
    int s = 0;
    #pragma unroll
    for (int i = 1; i < 4; ++i) if (bid >= p.blk0[i]) s = i;
    int local = bid - p.blk0[s];
    int K = p.K[s], N = p.N[s];
    int ntn = N >> 6, ntk = K >> 6, tpg = ntn * ntk;
    int g  = local / tpg;
    int t_ = local - g * tpg;
    int kt = t_ / ntn, nt = t_ - kt * ntn;
    const float* src = p.src[s] + (long)g * K * N;
    bf16_t*      dst = p.dst[s] + (long)g * K * N;
    int k0 = kt * 64, n0 = nt * 64;

    __shared__ float t[64][64];
    int tid = threadIdx.x;
    int kr = tid >> 4;             // 0..15
    int gn = tid & 15;             // n-granule
    #pragma unroll
    for (int i = 0; i < 4; ++i) {
        int k = kr + i * 16;
        float4 v = *(const float4*)(src + (long)(k0 + k) * N + n0 + gn * 4);
        *(float4*)&t[k][((gn ^ (k >> 3)) & 15) * 4] = v;
    }
    __syncthreads();
    int kc = tid & 7;              // k-chunk (8 elems)
    int nr = tid >> 3;             // 0..31
    #pragma unroll
    for (int h = 0; h < 2; ++h) {
        int n = nr + h * 32;
        us8 o;
        #pragma unroll
        for (int j = 0; j < 8; ++j) {
            int k = kc * 8 + j;
            o[j] = f2bfu(t[k][((((n >> 2) ^ kc) & 15) * 4) + (n & 3)]);
        }
        *(us8*)(dst + (long)(n0 + n) * K + k0 + kc * 8) = o;
    }
}

// ---------------- 32x32x16 MFMA GEMM (transformer layers)
// BK=64, double-buffered LDS, counted vmcnt + raw s_barrier (T3+T4),
// fragment-ordered LDS (linear dest, pre-permuted global src).
// EPI: 0 = none (bf16 out), 1 = +bias +resid (fp32 out), 2 = +bias gelu (bf16)
template<int BM, int BN, int WM, int WN, int EPI>
__global__ __launch_bounds__(256) void gemm32(
    const bf16_t* __restrict__ A, const bf16_t* __restrict__ BT,
    const float* __restrict__ bias, const float* __restrict__ resid,
    void* __restrict__ Cv,
    int M, int N, int K)
{
    constexpr int WAVES_N = BN / WN;
    constexpr int FM = WM / 32, FN = WN / 32;
    constexpr int NSTG = BM / 32 + BN / 32;
    float*  Cf = (float*)Cv;
    bf16_t* Ch = (bf16_t*)Cv;

    __shared__ bf16_t As[2][BM * 64];
    __shared__ bf16_t Bs[2][BN * 64];

    int tid  = threadIdx.x;
    int wave = tid >> 6, lane = tid & 63;
    int wr = wave / WAVES_N, wc = wave % WAVES_N;
    int m0 = blockIdx.y * BM, n0 = blockIdx.x * BN;

    f32x16 acc[FM][FN];
    #pragma unroll
    for (int m = 0; m < FM; ++m)
        #pragma unroll
        for (int n = 0; n < FN; ++n)
            #pragma unroll
            for (int r = 0; r < 16; ++r)
                acc[m][n][r] = 0.f;

    long rsb = (long)K * 2;                  // row byte stride
    int  lr  = lane & 31;                    // fragment row within subtile
    int  lkb = (lane >> 5) * 16;             // 16B k-chunk within 32B row-span

    const char* Abase = (const char*)A + (long)(m0 + lr) * rsb + lkb;
    const char* Bbase = (const char*)BT + (long)(n0 + lr) * rsb + lkb;

    auto stage = [&](int c, int t) {
        long kb = (long)t * 128;             // t*64 k * 2B
        #pragma unroll
        for (int i = 0; i < BM / 32; ++i) {
            int b = i * 4 + wave;
            gload_lds16(Abase + (long)(b >> 2) * 32 * rsb + (b & 3) * 32 + kb,
                        (char*)&As[c][0] + b * 1024);
        }
        #pragma unroll
        for (int i = 0; i < BN / 32; ++i) {
            int b = i * 4 + wave;
            gload_lds16(Bbase + (long)(b >> 2) * 32 * rsb + (b & 3) * 32 + kb,
                        (char*)&Bs[c][0] + b * 1024);
        }
    };

    int nt = K >> 6;
    stage(0, 0);
    int cur = 0;
    for (int t = 0; t < nt; ++t) {
        if (t + 1 < nt) {
            stage(cur ^ 1, t + 1);
            asm volatile("s_waitcnt vmcnt(%c0)" :: "i"(NSTG) : "memory");
        } else {
            asm volatile("s_waitcnt vmcnt(0)" ::: "memory");
        }
        __builtin_amdgcn_s_barrier();
        asm volatile("" ::: "memory");
        bf16x8 af[FM][4], bq[FN][4];
        #pragma unroll
        for (int m = 0; m < FM; ++m)
            #pragma unroll
            for (int kk = 0; kk < 4; ++kk)
                af[m][kk] = *(const bf16x8*)((const char*)&As[cur][0] +
                            ((wr * FM + m) * 4 + kk) * 1024 + (lane << 4));
        #pragma unroll
        for (int n = 0; n < FN; ++n)
            #pragma unroll
            for (int kk = 0; kk < 4; ++kk)
                bq[n][kk] = *(const bf16x8*)((const char*)&Bs[cur][0] +
                            ((wc * FN + n) * 4 + kk) * 1024 + (lane << 4));
        #pragma unroll
        for (int kk = 0; kk < 4; ++kk)
            #pragma unroll
            for (int m = 0; m < FM; ++m)
                #pragma unroll
                for (int n = 0; n < FN; ++n)
                    acc[m][n] = __builtin_amdgcn_mfma_f32_32x32x16_bf16(
                        af[m][kk], bq[n][kk], acc[m][n], 0, 0, 0);
        asm volatile("" ::: "memory");
        __builtin_amdgcn_s_barrier();
        cur ^= 1;
    }

    // C/D layout: col = lane&31, row = (reg&3) + 8*(reg>>2) + 4*(lane>>5)
    int rbase = 4 * (lane >> 5);
    #pragma unroll
    for (int m = 0; m < FM; ++m) {
        #pragma unroll
        for (int n = 0; n < FN; ++n) {
            int colI = n0 + wc * WN + n * 32 + (lane & 31);
            float bb = (EPI != 0) ? bias[colI] : 0.f;
            #pragma unroll
            for (int r = 0; r < 16; ++r) {
                int rowI = m0 + wr * WM + m * 32 + rbase + (r & 3) + 8 * (r >> 2);
                float v = acc[m][n][r] + bb;
                if (EPI == 2) v = 0.5f * v * (1.0f + erff(v * 0.70710678118654752f));
                long off = (long)rowI * N + colI;
                if (EPI == 1)      Cf[off] = v + resid[off];
                else               Ch[off] = (bf16_t)v;
            }
        }
    }
}

// ---------------- head GEMM: A bf16 [M][K] (fragment-ordered), B fp32 NATIVE [K][N]
// 64x64 tile, 4 waves (2x2 of 32x32), 16x16x32 MFMA, relu epilogue, bf16 out.
// Double-buffered, counted vmcnt + raw barriers. M == 64.
__global__ __launch_bounds__(256) void gemm_hd(
    const bf16_t* __restrict__ A, const float* __restrict__ Bw,
    const float* __restrict__ bias, bf16_t* __restrict__ C,
    int N, int K, long sA, long sB, long sbias, long sC)
{
    long g = blockIdx.z;
    A += g * sA;
    const float* Bp = Bw + g * sB;
    bias += g * sbias;
    bf16_t* Cp = C + g * sC;

    __shared__ bf16_t As[2][64 * 64];
    __shared__ float  Bf[2][64 * 64];

    int tid = threadIdx.x, wave = tid >> 6, lane = tid & 63;
    int wr = wave >> 1, wc = wave & 1;
    int n0 = blockIdx.x * 64;

    f32x4 acc[2][2];
    #pragma unroll
    for (int m = 0; m < 2; ++m)
        #pragma unroll
        for (int n = 0; n < 2; ++n)
            acc[m][n] = f32x4{0.f, 0.f, 0.f, 0.f};

    long rsb = (long)K * 2;
    int  lr  = lane & 15;
    int  lkb = (lane >> 4) * 16;
    const char* Abase = (const char*)A + (long)lr * rsb + lkb;   // m0 = 0

    auto stage = [&](int c, int t) {
        long kb = (long)t * 128;
        #pragma unroll
        for (int i = 0; i < 2; ++i) {            // A: 64x64 bf16, fragment-ordered
            int b = i * 4 + wave;
            gload_lds16(Abase + (long)(b >> 1) * 16 * rsb + (b & 1) * 64 + kb,
                        (char*)&As[c][0] + b * 1024);
        }
        #pragma unroll
        for (int i = 0; i < 4; ++i) {            // B: 64k x 64n fp32 row-major
            int ch = i * 4 + wave;
            int row = ch * 4 + (lane >> 4);
            gload_lds16((const char*)Bp + ((long)(t * 64 + row) * N + n0) * 4 + (lane & 15) * 16,
                        (char*)&Bf[c][0] + ch * 1024);
        }
    };

    int nt = K >> 6;
    stage(0, 0);
    int cur = 0;
    for (int t = 0; t < nt; ++t) {
        if (t + 1 < nt) {
            stage(cur ^ 1, t + 1);
            asm volatile("s_waitcnt vmcnt(6)" ::: "memory");
        } else {
            asm volatile("s_waitcnt vmcnt(0)" ::: "memory");
        }
        __builtin_amdgcn_s_barrier();
        asm volatile("" ::: "memory");
        bf16x8 af[2][2], bq[2][2];
        #pragma unroll
        for (int m = 0; m < 2; ++m)
            #pragma unroll
            for (int h = 0; h < 2; ++h)
                af[m][h] = *(const bf16x8*)((const char*)&As[cur][0] +
                           ((wr * 2 + m) * 2 + h) * 1024 + (lane << 4));
        #pragma unroll
        for (int n = 0; n < 2; ++n) {
            int nl = wc * 32 + n * 16 + lr;
            #pragma unroll
            for (int h = 0; h < 2; ++h) {
                #pragma unroll
                for (int j = 0; j < 8; ++j) {
                    float v = Bf[cur][(h * 32 + (lane >> 4) * 8 + j) * 64 + nl];
                    bq[n][h][j] = (bf16_t)v;
                }
            }
        }
        #pragma unroll
        for (int h = 0; h < 2; ++h)
            #pragma unroll
            for (int m = 0; m < 2; ++m)
                #pragma unroll
                for (int n = 0; n < 2; ++n)
                    acc[m][n] = __builtin_amdgcn_mfma_f32_16x16x32_bf16(
                        af[m][h], bq[n][h], acc[m][n], 0, 0, 0);
        asm volatile("" ::: "memory");
        __builtin_amdgcn_s_barrier();
        cur ^= 1;
    }

    int lq = (lane >> 4) * 4;
    #pragma unroll
    for (int m = 0; m < 2; ++m) {
        #pragma unroll
        for (int n = 0; n < 2; ++n) {
            int colI = n0 + wc * 32 + n * 16 + lr;
            float bb = bias[colI];
            #pragma unroll
            for (int j = 0; j < 4; ++j) {
                int rowI = wr * 32 + m * 16 + lq + j;
                float v = fmaxf(acc[m][n][j] + bb, 0.0f);
                Cp[(long)rowI * N + colI] = (bf16_t)v;
            }
        }
    }
}

// ---------------- fused attention: one block per (batch, head). T=32, HD=64.
// f4-vectorized scores/PV phases, swizzled K^T tile, conflict-free LDS reads.
__global__ __launch_bounds__(256) void attn_kernel(const bf16_t* __restrict__ qkv,
                                                   bf16_t* __restrict__ o) {
    int bh = blockIdx.x;
    int b  = bh >> 4;
    int hh = bh & 15;
    __shared__ float qs[32][65];   // [q][d], pad 65: conflict-free scalar access
    __shared__ float kt[64][36];   // [d][c], granule-swizzled, f4-readable
    __shared__ float vs[32][68];   // [c][d], pad 68: f4-readable rows
    __shared__ float ps[32][33];
    const bf16_t* base = qkv + (long)b * SEQ * (3 * DIM) + hh * HDIM;
    int tid = threadIdx.x;

    {   // load: 256 threads cover 32 rows x 8 chunks of 8 elems
        int t = tid >> 3, c = (tid & 7) * 8;
        bf16x8 qv = *(const bf16x8*)(base + (long)t * 3 * DIM + c);
        bf16x8 kv = *(const bf16x8*)(base + (long)t * 3 * DIM + DIM + c);
        bf16x8 vv = *(const bf16x8*)(base + (long)t * 3 * DIM + 2 * DIM + c);
        #pragma unroll
        for (int j = 0; j < 8; ++j) {
            int d = c + j;
            qs[t][d] = (float)qv[j];
            // kt[d][c'] with granule swizzle: col = ((t>>2)^((d>>2)&7))*4 + (t&3)
            kt[d][(((t >> 2) ^ ((d >> 2) & 7)) << 2) + (t & 3)] = (float)kv[j];
            vs[t][d] = (float)vv[j];
        }
    }
    __syncthreads();

    {   // scores: thread -> (row r, cols c0..c0+3)
        int r  = tid >> 3;            // 0..31
        int c0 = (tid & 7) * 4;       // 0..28
        f32x4 acc = {0.f, 0.f, 0.f, 0.f};
        #pragma unroll
        for (int d = 0; d < 64; ++d) {
            float qv = qs[r][d];
            float4 kv = *(const float4*)&kt[d][(((c0 >> 2) ^ ((d >> 2) & 7)) << 2)];
            acc[0] = fmaf(qv, kv.x, acc[0]);
            acc[1] = fmaf(qv, kv.y, acc[1]);
            acc[2] = fmaf(qv, kv.z, acc[2]);
            acc[3] = fmaf(qv, kv.w, acc[3]);
        }
        #pragma unroll
        for (int i = 0; i < 4; ++i) ps[r][c0 + i] = acc[i] * 0.125f;
    }
    __syncthreads();

    if (tid < 32) {                   // softmax per row
        float mx = -1e30f;
        for (int c = 0; c < 32; ++c) mx = fmaxf(mx, ps[tid][c]);
        float sum = 0.f;
        for (int c = 0; c < 32; ++c) { float e = expf(ps[tid][c] - mx); ps[tid][c] = e; sum += e; }
        float inv = 1.f / sum;
        for (int c = 0; c < 32; ++c) ps[tid][c] *= inv;
    }
    __syncthreads();

    {   // PV: thread -> (row r, d0..d0+7)
        int r  = tid >> 3;            // 0..31
        int d0 = (tid & 7) * 8;       // 0..56
        float acc[8] = {};
        #pragma unroll
        for (int c = 0; c < 32; ++c) {
            float pv = ps[r][c];
            float4 v0 = *(const float4*)&vs[c][d0];
            float4 v1 = *(const float4*)&vs[c][d0 + 4];
            acc[0] = fmaf(pv, v0.x, acc[0]);
            acc[1] = fmaf(pv, v0.y, acc[1]);
            acc[2] = fmaf(pv, v0.z, acc[2]);
            acc[3] = fmaf(pv, v0.w, acc[3]);
            acc[4] = fmaf(pv, v1.x, acc[4]);
            acc[5] = fmaf(pv, v1.y, acc[5]);
            acc[6] = fmaf(pv, v1.z, acc[6]);
            acc[7] = fmaf(pv, v1.w, acc[7]);
        }
        us8 ov;
        #pragma unroll
        for (int j = 0; j < 8; ++j) ov[j] = f2bfu(acc[j]);
        *(us8*)(o + (long)b * SEQ * DIM + (long)r * DIM + hh * HDIM + d0) = ov;
    }
}

// ---------------- x_comb -> bf16
__global__ void comb_kernel(const float* __restrict__ h, bf16_t* __restrict__ xc) {
    int i = blockIdx.x * 256 + threadIdx.x;
    int b = i >> 11;
    int c = i & 2047;
    xc[i] = (bf16_t)h[(long)b * (SEQ * DIM) + c];
}

// ---------------- head layer 3: one wave per (n, b), dot-512
__global__ __launch_bounds__(256) void head3_kernel(const bf16_t* __restrict__ h2,
                                                    const float* __restrict__ w3,
                                                    const float* __restrict__ b3,
                                                    float* __restrict__ out) {
    int gid  = blockIdx.x * 256 + threadIdx.x;
    int wave = gid >> 6;
    int lane = gid & 63;
    if (wave >= NHEAD_OUT * BATCH) return;
    int n = wave >> 6;
    int b = wave & 63;
    const bf16_t* a = h2 + ((long)n * BATCH + b) * IDH;
    const float*  w = w3 + (long)n * IDH;
    float acc = 0.f;
    #pragma unroll
    for (int i = lane; i < IDH; i += 64) acc = fmaf((float)a[i], w[i], acc);
    #pragma unroll
    for (int off = 32; off > 0; off >>= 1) acc += __shfl_down(acc, off);
    if (lane == 0) out[b * NHEAD_OUT + n] = acc + b3[n];
}

extern "C" void kernel_launch(void* const* d_in, const int* in_sizes, int n_in,
                              void* d_out, int out_size, void* d_ws, size_t ws_size,
                              hipStream_t stream) {
    const float* x      = (const float*)d_in[0];
    const float* qkv_w  = (const float*)d_in[1];
    const float* out_w  = (const float*)d_in[2];
    const float* out_b  = (const float*)d_in[3];
    const float* attn_g = (const float*)d_in[4];
    const float* attn_b = (const float*)d_in[5];
    const float* ff_g   = (const float*)d_in[6];
    const float* ff_b   = (const float*)d_in[7];
    const float* ff_w1  = (const float*)d_in[8];
    const float* ff_b1  = (const float*)d_in[9];
    const float* ff_w2  = (const float*)d_in[10];
    const float* ff_b2  = (const float*)d_in[11];
    const float* hw1    = (const float*)d_in[12];
    const float* hb1    = (const float*)d_in[13];
    const float* hw2    = (const float*)d_in[14];
    const float* hb2    = (const float*)d_in[15];
    const float* hw3    = (const float*)d_in[16];
    const float* hb3    = (const float*)d_in[17];
    float* out = (float*)d_out;

    char* p = (char*)d_ws;
    float*  h     = (float*)p;            p += (long)TOK * DIM * 4;
    bf16_t* qkvb  = (bf16_t*)p;           p += (long)TOK * 3 * DIM * 2;
    bf16_t* y     = (bf16_t*)p;           p += (long)TOK * DIM * 2;
    bf16_t* ob    = (bf16_t*)p;           p += (long)TOK * DIM * 2;
    bf16_t* ffb   = (bf16_t*)p;           p += (long)TOK * FFD * 2;
    bf16_t* xc    = (bf16_t*)p;           p += (long)BATCH * 2 * DIM * 2;
    bf16_t* h1    = (bf16_t*)p;           p += (long)NHEAD_OUT * BATCH * IDH * 2;
    bf16_t* h2    = (bf16_t*)p;           p += (long)NHEAD_OUT * BATCH * IDH * 2;
    bf16_t* qkvwt = (bf16_t*)p;           p += (long)LAYERS * DIM * 3 * DIM * 2;
    bf16_t* outwt = (bf16_t*)p;           p += (long)LAYERS * DIM * DIM * 2;
    bf16_t* ff1t  = (bf16_t*)p;           p += (long)LAYERS * DIM * FFD * 2;
    bf16_t* ff2t  = (bf16_t*)p;           p += (long)LAYERS * FFD * DIM * 2;

    // ---- transformer weight transpose+convert (heads excluded) ----
    TxPack tp;
    tp.src[0] = qkv_w; tp.dst[0] = qkvwt; tp.K[0] = DIM; tp.N[0] = 3 * DIM;
    tp.src[1] = out_w; tp.dst[1] = outwt; tp.K[1] = DIM; tp.N[1] = DIM;
    tp.src[2] = ff_w1; tp.dst[2] = ff1t;  tp.K[2] = DIM; tp.N[2] = FFD;
    tp.src[3] = ff_w2; tp.dst[3] = ff2t;  tp.K[3] = FFD; tp.N[3] = DIM;
    int nblk = 0;
    for (int i = 0; i < 4; ++i) {
        tp.blk0[i] = nblk;
        nblk += LAYERS * (tp.K[i] >> 6) * (tp.N[i] >> 6);
    }
    tx64<<<nblk, 256, 0, stream>>>(tp);

    hipMemcpyAsync(h, x, (size_t)TOK * DIM * sizeof(float),
                   hipMemcpyDeviceToDevice, stream);

    for (int l = 0; l < LAYERS; ++l) {
        ln_kernel<true><<<TOK, 256, 0, stream>>>(h, attn_g + l * DIM, attn_b + l * DIM, y);
        gemm32<64, 128, 32, 64, 0><<<dim3(3 * DIM / 128, TOK / 64), 256, 0, stream>>>(
            y, qkvwt + (long)l * DIM * 3 * DIM, nullptr, nullptr, qkvb,
            TOK, 3 * DIM, DIM);
        attn_kernel<<<BATCH * NH, 256, 0, stream>>>(qkvb, ob);
        gemm32<64, 64, 32, 32, 1><<<dim3(DIM / 64, TOK / 64), 256, 0, stream>>>(
            ob, outwt + (long)l * DIM * DIM, out_b + l * DIM, h, h,
            TOK, DIM, DIM);
        ln_kernel<false><<<TOK, 256, 0, stream>>>(h, ff_g + l * DIM, ff_b + l * DIM, y);
        gemm32<64, 128, 32, 64, 2><<<dim3(FFD / 128, TOK / 64), 256, 0, stream>>>(
            y, ff1t + (long)l * DIM * FFD, ff_b1 + l * FFD, nullptr, ffb,
            TOK, FFD, DIM);
        gemm32<64, 64, 32, 32, 1><<<dim3(DIM / 64, TOK / 64), 256, 0, stream>>>(
            ffb, ff2t + (long)l * FFD * DIM, ff_b2 + l * DIM, h, h,
            TOK, DIM, FFD);
    }

    comb_kernel<<<(BATCH * 2 * DIM) / 256, 256, 0, stream>>>(h, xc);

    // heads: fp32 weights read natively, no transpose pass
    gemm_hd<<<dim3(IDH / 64, 1, NHEAD_OUT), 256, 0, stream>>>(
        xc, hw1, hb1, h1,
        IDH, 2 * DIM, 0, (long)2 * DIM * IDH, IDH, (long)BATCH * IDH);
    gemm_hd<<<dim3(IDH / 64, 1, NHEAD_OUT), 256, 0, stream>>>(
        h1, hw2, hb2, h2,
        IDH, IDH, (long)BATCH * IDH, (long)IDH * IDH, IDH, (long)BATCH * IDH);
    head3_kernel<<<(NHEAD_OUT * BATCH * 64) / 256, 256, 0, stream>>>(h2, hw3, hb3, out);
}

// Round 9
// 537.265 us; speedup vs baseline: 1.6072x; 1.2180x over previous
//
#include <hip/hip_runtime.h>
#include <math.h>

static constexpr int BATCH = 64;
static constexpr int SEQ   = 32;
static constexpr int TOK   = BATCH * SEQ;   // 2048
static constexpr int DIM   = 1024;
static constexpr int NH    = 16;
static constexpr int HDIM  = 64;
static constexpr int FFD   = 2048;
static constexpr int LAYERS= 4;
static constexpr int NHEAD_OUT = 26;
static constexpr int IDH   = 512;

typedef __bf16 bf16_t;
typedef __bf16 bf16x8 __attribute__((ext_vector_type(8)));
typedef float  f32x4  __attribute__((ext_vector_type(4)));
typedef float  f32x16 __attribute__((ext_vector_type(16)));
typedef unsigned short us4 __attribute__((ext_vector_type(4)));
typedef unsigned short us8 __attribute__((ext_vector_type(8)));

__device__ __forceinline__ unsigned short f2bfu(float f) {
    return __builtin_bit_cast(unsigned short, (bf16_t)f);
}

__device__ __forceinline__ void gload_lds16(const void* gp, void* lp) {
    __builtin_amdgcn_global_load_lds(
        (const __attribute__((address_space(1))) unsigned int*)gp,
        (__attribute__((address_space(3))) unsigned int*)lp,
        16, 0, 0);
}

// ---------------- block-wide sum (256 threads = 4 waves) ----------------
__device__ __forceinline__ float block_sum(float v, float* red) {
    #pragma unroll
    for (int off = 32; off > 0; off >>= 1) v += __shfl_down(v, off);
    int lane = threadIdx.x & 63;
    int w    = threadIdx.x >> 6;
    if (lane == 0) red[w] = v;
    __syncthreads();
    float t = red[0] + red[1] + red[2] + red[3];
    __syncthreads();
    return t;
}

// ---------------- LayerNorm -> bf16 output
template<bool PRE>
__global__ __launch_bounds__(256) void ln_kernel(const float* __restrict__ x,
                                                 const float* __restrict__ g,
                                                 const float* __restrict__ b,
                                                 bf16_t* __restrict__ y) {
    __shared__ float red[4];
    long row = blockIdx.x;
    const float* xr = x + row * DIM;
    int tid = threadIdx.x;
    float4 v = *(const float4*)(xr + tid * 4);
    if (PRE) {
        float s  = block_sum(v.x + v.y + v.z + v.w, red);
        float mu = s * (1.0f / DIM);
        v.x -= mu; v.y -= mu; v.z -= mu; v.w -= mu;
        float ss = block_sum(v.x*v.x + v.y*v.y + v.z*v.z + v.w*v.w, red);
        float r  = 1.0f / sqrtf(ss * (1.0f / DIM) + 1e-6f);
        v.x *= r; v.y *= r; v.z *= r; v.w *= r;
    }
    float s  = block_sum(v.x + v.y + v.z + v.w, red);
    float mu = s * (1.0f / DIM);
    v.x -= mu; v.y -= mu; v.z -= mu; v.w -= mu;
    float ss = block_sum(v.x*v.x + v.y*v.y + v.z*v.z + v.w*v.w, red);
    float r  = 1.0f / sqrtf(ss * (1.0f / DIM) + 1e-5f);
    float4 gg = *(const float4*)(g + tid * 4);
    float4 bb = *(const float4*)(b + tid * 4);
    us4 o;
    o.x = f2bfu(v.x * r * gg.x + bb.x);
    o.y = f2bfu(v.y * r * gg.y + bb.y);
    o.z = f2bfu(v.z * r * gg.z + bb.z);
    o.w = f2bfu(v.w * r * gg.w + bb.w);
    *(us4*)(y + row * DIM + tid * 4) = o;
}

// ---------------- merged transpose+cvt -> FRAGMENT-TILED layout
// Output chunk for (n_sub of 32 rows, t of 64 k) = 4KB: [kk(4)][lane(64)][16B],
// lane l holds n = n_sub*32 + (l&31), k = kk*16 + (l>>5)*8 + j (j=0..7).
// Block writes its 2 chunks fully -> perfect write coalescing; GEMM stages
// each chunk with ONE fully-contiguous global_load_lds per kk.
struct TxPack {
    const float* src[4];
    bf16_t*      dst[4];
    int K[4], N[4];
    int blk0[4];
};

__global__ __launch_bounds__(256) void tx64(TxPack p) {
    int bid = blockIdx.x;
    int s = 0;
    #pragma unroll
    for (int i = 1; i < 4; ++i) if (bid >= p.blk0[i]) s = i;
    int local = bid - p.blk0[s];
    int K = p.K[s], N = p.N[s];
    int ntn = N >> 6, ntk = K >> 6, tpg = ntn * ntk;
    int g  = local / tpg;
    int t_ = local - g * tpg;
    int kt = t_ / ntn, nt = t_ - kt * ntn;
    const float* src = p.src[s] + (long)g * K * N;
    bf16_t*      dst = p.dst[s] + (long)g * K * N;
    int k0 = kt * 64, n0 = nt * 64;

    __shared__ float t[64][64];
    int tid = threadIdx.x;
    int kr = tid >> 4;             // 0..15
    int gn = tid & 15;             // n-granule
    #pragma unroll
    for (int i = 0; i < 4; ++i) {
        int k = kr + i * 16;
        float4 v = *(const float4*)(src + (long)(k0 + k) * N + n0 + gn * 4);
        *(float4*)&t[k][((gn ^ (k >> 3)) & 15) * 4] = v;
    }
    __syncthreads();
    int kc = tid & 7;              // k-chunk (8 elems), kc*8 .. kc*8+7
    int nr = tid >> 3;             // 0..31
    int nkb = K >> 6;
    #pragma unroll
    for (int h = 0; h < 2; ++h) {
        int n = nr + h * 32;
        us8 o;
        #pragma unroll
        for (int j = 0; j < 8; ++j) {
            int k = kc * 8 + j;
            o[j] = f2bfu(t[k][((((n >> 2) ^ kc) & 15) * 4) + (n & 3)]);
        }
        // tiled dst: chunk ((n0>>5)+h, kt), within: kk=kc>>1, lane = nr + 32*(kc&1)
        long off = (((long)(n0 >> 5) + h) * nkb + kt) * 2048
                 + (kc >> 1) * 512 + (nr + 32 * (kc & 1)) * 8;
        *(us8*)(dst + off) = o;
    }
}

// ---------------- 32x32x16 MFMA GEMM (transformer layers)
// BK=64, double-buffered LDS, counted vmcnt + raw s_barrier.
// A: row-major bf16, fragment-order-permuted per-lane src (32B segments, L2-hot).
// B: FRAGMENT-TILED bf16 (tx64 layout) -> 1KB contiguous per gload_lds.
// EPI: 0 = none (bf16 out), 1 = +bias +resid (fp32 out), 2 = +bias gelu (bf16)
template<int BM, int BN, int WM, int WN, int EPI>
__global__ __launch_bounds__(256) void gemm32(
    const bf16_t* __restrict__ A, const bf16_t* __restrict__ BT,
    const float* __restrict__ bias, const float* __restrict__ resid,
    void* __restrict__ Cv,
    int M, int N, int K)
{
    constexpr int WAVES_N = BN / WN;
    constexpr int FM = WM / 32, FN = WN / 32;
    constexpr int NSTG = BM / 32 + BN / 32;
    float*  Cf = (float*)Cv;
    bf16_t* Ch = (bf16_t*)Cv;

    __shared__ bf16_t As[2][BM * 64];
    __shared__ bf16_t Bs[2][BN * 64];

    int tid  = threadIdx.x;
    int wave = tid >> 6, lane = tid & 63;
    int wr = wave / WAVES_N, wc = wave % WAVES_N;
    int m0 = blockIdx.y * BM, n0 = blockIdx.x * BN;

    f32x16 acc[FM][FN];
    #pragma unroll
    for (int m = 0; m < FM; ++m)
        #pragma unroll
        for (int n = 0; n < FN; ++n)
            #pragma unroll
            for (int r = 0; r < 16; ++r)
                acc[m][n][r] = 0.f;

    long rsb = (long)K * 2;                  // row byte stride (A)
    int  lr  = lane & 31;
    int  lkb = (lane >> 5) * 16;
    int  nkb = K >> 6;

    const char* Abase = (const char*)A + (long)(m0 + lr) * rsb + lkb;
    const char* Bbase = (const char*)BT + (long)(n0 >> 5) * nkb * 4096 + lane * 16;

    auto stage = [&](int c, int t) {
        long kb = (long)t * 128;             // t*64 k * 2B (A side)
        #pragma unroll
        for (int i = 0; i < BM / 32; ++i) {
            int b = i * 4 + wave;
            gload_lds16(Abase + (long)(b >> 2) * 32 * rsb + (b & 3) * 32 + kb,
                        (char*)&As[c][0] + b * 1024);
        }
        #pragma unroll
        for (int i = 0; i < BN / 32; ++i) {
            int b = i * 4 + wave;            // s = b>>2, kk = b&3
            gload_lds16(Bbase + ((long)(b >> 2) * nkb + t) * 4096 + (b & 3) * 1024,
                        (char*)&Bs[c][0] + b * 1024);
        }
    };

    int nt = K >> 6;
    stage(0, 0);
    int cur = 0;
    for (int t = 0; t < nt; ++t) {
        if (t + 1 < nt) {
            stage(cur ^ 1, t + 1);
            asm volatile("s_waitcnt vmcnt(%c0)" :: "i"(NSTG) : "memory");
        } else {
            asm volatile("s_waitcnt vmcnt(0)" ::: "memory");
        }
        __builtin_amdgcn_s_barrier();
        asm volatile("" ::: "memory");
        bf16x8 af[FM][4], bq[FN][4];
        #pragma unroll
        for (int m = 0; m < FM; ++m)
            #pragma unroll
            for (int kk = 0; kk < 4; ++kk)
                af[m][kk] = *(const bf16x8*)((const char*)&As[cur][0] +
                            ((wr * FM + m) * 4 + kk) * 1024 + (lane << 4));
        #pragma unroll
        for (int n = 0; n < FN; ++n)
            #pragma unroll
            for (int kk = 0; kk < 4; ++kk)
                bq[n][kk] = *(const bf16x8*)((const char*)&Bs[cur][0] +
                            ((wc * FN + n) * 4 + kk) * 1024 + (lane << 4));
        #pragma unroll
        for (int kk = 0; kk < 4; ++kk)
            #pragma unroll
            for (int m = 0; m < FM; ++m)
                #pragma unroll
                for (int n = 0; n < FN; ++n)
                    acc[m][n] = __builtin_amdgcn_mfma_f32_32x32x16_bf16(
                        af[m][kk], bq[n][kk], acc[m][n], 0, 0, 0);
        asm volatile("" ::: "memory");
        __builtin_amdgcn_s_barrier();
        cur ^= 1;
    }

    // C/D layout: col = lane&31, row = (reg&3) + 8*(reg>>2) + 4*(lane>>5)
    int rbase = 4 * (lane >> 5);
    #pragma unroll
    for (int m = 0; m < FM; ++m) {
        #pragma unroll
        for (int n = 0; n < FN; ++n) {
            int colI = n0 + wc * WN + n * 32 + (lane & 31);
            float bb = (EPI != 0) ? bias[colI] : 0.f;
            #pragma unroll
            for (int r = 0; r < 16; ++r) {
                int rowI = m0 + wr * WM + m * 32 + rbase + (r & 3) + 8 * (r >> 2);
                float v = acc[m][n][r] + bb;
                if (EPI == 2) v = 0.5f * v * (1.0f + erff(v * 0.70710678118654752f));
                long off = (long)rowI * N + colI;
                if (EPI == 1)      Cf[off] = v + resid[off];
                else               Ch[off] = (bf16_t)v;
            }
        }
    }
}

// ---------------- head GEMM: A bf16 [M][K] (fragment-ordered), B fp32 NATIVE [K][N]
__global__ __launch_bounds__(256) void gemm_hd(
    const bf16_t* __restrict__ A, const float* __restrict__ Bw,
    const float* __restrict__ bias, bf16_t* __restrict__ C,
    int N, int K, long sA, long sB, long sbias, long sC)
{
    long g = blockIdx.z;
    A += g * sA;
    const float* Bp = Bw + g * sB;
    bias += g * sbias;
    bf16_t* Cp = C + g * sC;

    __shared__ bf16_t As[2][64 * 64];
    __shared__ float  Bf[2][64 * 64];

    int tid = threadIdx.x, wave = tid >> 6, lane = tid & 63;
    int wr = wave >> 1, wc = wave & 1;
    int n0 = blockIdx.x * 64;

    f32x4 acc[2][2];
    #pragma unroll
    for (int m = 0; m < 2; ++m)
        #pragma unroll
        for (int n = 0; n < 2; ++n)
            acc[m][n] = f32x4{0.f, 0.f, 0.f, 0.f};

    long rsb = (long)K * 2;
    int  lr  = lane & 15;
    int  lkb = (lane >> 4) * 16;
    const char* Abase = (const char*)A + (long)lr * rsb + lkb;   // m0 = 0

    auto stage = [&](int c, int t) {
        long kb = (long)t * 128;
        #pragma unroll
        for (int i = 0; i < 2; ++i) {            // A: 64x64 bf16, fragment-ordered
            int b = i * 4 + wave;
            gload_lds16(Abase + (long)(b >> 1) * 16 * rsb + (b & 1) * 64 + kb,
                        (char*)&As[c][0] + b * 1024);
        }
        #pragma unroll
        for (int i = 0; i < 4; ++i) {            // B: 64k x 64n fp32 row-major
            int ch = i * 4 + wave;
            int row = ch * 4 + (lane >> 4);
            gload_lds16((const char*)Bp + ((long)(t * 64 + row) * N + n0) * 4 + (lane & 15) * 16,
                        (char*)&Bf[c][0] + ch * 1024);
        }
    };

    int nt = K >> 6;
    stage(0, 0);
    int cur = 0;
    for (int t = 0; t < nt; ++t) {
        if (t + 1 < nt) {
            stage(cur ^ 1, t + 1);
            asm volatile("s_waitcnt vmcnt(6)" ::: "memory");
        } else {
            asm volatile("s_waitcnt vmcnt(0)" ::: "memory");
        }
        __builtin_amdgcn_s_barrier();
        asm volatile("" ::: "memory");
        bf16x8 af[2][2], bq[2][2];
        #pragma unroll
        for (int m = 0; m < 2; ++m)
            #pragma unroll
            for (int h = 0; h < 2; ++h)
                af[m][h] = *(const bf16x8*)((const char*)&As[cur][0] +
                           ((wr * 2 + m) * 2 + h) * 1024 + (lane << 4));
        #pragma unroll
        for (int n = 0; n < 2; ++n) {
            int nl = wc * 32 + n * 16 + lr;
            #pragma unroll
            for (int h = 0; h < 2; ++h) {
                #pragma unroll
                for (int j = 0; j < 8; ++j) {
                    float v = Bf[cur][(h * 32 + (lane >> 4) * 8 + j) * 64 + nl];
                    bq[n][h][j] = (bf16_t)v;
                }
            }
        }
        #pragma unroll
        for (int h = 0; h < 2; ++h)
            #pragma unroll
            for (int m = 0; m < 2; ++m)
                #pragma unroll
                for (int n = 0; n < 2; ++n)
                    acc[m][n] = __builtin_amdgcn_mfma_f32_16x16x32_bf16(
                        af[m][h], bq[n][h], acc[m][n], 0, 0, 0);
        asm volatile("" ::: "memory");
        __builtin_amdgcn_s_barrier();
        cur ^= 1;
    }

    int lq = (lane >> 4) * 4;
    #pragma unroll
    for (int m = 0; m < 2; ++m) {
        #pragma unroll
        for (int n = 0; n < 2; ++n) {
            int colI = n0 + wc * 32 + n * 16 + lr;
            float bb = bias[colI];
            #pragma unroll
            for (int j = 0; j < 4; ++j) {
                int rowI = wr * 32 + m * 16 + lq + j;
                float v = fmaxf(acc[m][n][j] + bb, 0.0f);
                Cp[(long)rowI * N + colI] = (bf16_t)v;
            }
        }
    }
}

// ---------------- fused attention: one block per (batch, head). T=32, HD=64.
__global__ __launch_bounds__(256) void attn_kernel(const bf16_t* __restrict__ qkv,
                                                   bf16_t* __restrict__ o) {
    int bh = blockIdx.x;
    int b  = bh >> 4;
    int hh = bh & 15;
    __shared__ float qs[32][65];
    __shared__ float kt[64][36];
    __shared__ float vs[32][68];
    __shared__ float ps[32][33];
    const bf16_t* base = qkv + (long)b * SEQ * (3 * DIM) + hh * HDIM;
    int tid = threadIdx.x;

    {
        int t = tid >> 3, c = (tid & 7) * 8;
        bf16x8 qv = *(const bf16x8*)(base + (long)t * 3 * DIM + c);
        bf16x8 kv = *(const bf16x8*)(base + (long)t * 3 * DIM + DIM + c);
        bf16x8 vv = *(const bf16x8*)(base + (long)t * 3 * DIM + 2 * DIM + c);
        #pragma unroll
        for (int j = 0; j < 8; ++j) {
            int d = c + j;
            qs[t][d] = (float)qv[j];
            kt[d][(((t >> 2) ^ ((d >> 2) & 7)) << 2) + (t & 3)] = (float)kv[j];
            vs[t][d] = (float)vv[j];
        }
    }
    __syncthreads();

    {
        int r  = tid >> 3;
        int c0 = (tid & 7) * 4;
        f32x4 acc = {0.f, 0.f, 0.f, 0.f};
        #pragma unroll
        for (int d = 0; d < 64; ++d) {
            float qv = qs[r][d];
            float4 kv = *(const float4*)&kt[d][(((c0 >> 2) ^ ((d >> 2) & 7)) << 2)];
            acc[0] = fmaf(qv, kv.x, acc[0]);
            acc[1] = fmaf(qv, kv.y, acc[1]);
            acc[2] = fmaf(qv, kv.z, acc[2]);
            acc[3] = fmaf(qv, kv.w, acc[3]);
        }
        #pragma unroll
        for (int i = 0; i < 4; ++i) ps[r][c0 + i] = acc[i] * 0.125f;
    }
    __syncthreads();

    if (tid < 32) {
        float mx = -1e30f;
        for (int c = 0; c < 32; ++c) mx = fmaxf(mx, ps[tid][c]);
        float sum = 0.f;
        for (int c = 0; c < 32; ++c) { float e = expf(ps[tid][c] - mx); ps[tid][c] = e; sum += e; }
        float inv = 1.f / sum;
        for (int c = 0; c < 32; ++c) ps[tid][c] *= inv;
    }
    __syncthreads();

    {
        int r  = tid >> 3;
        int d0 = (tid & 7) * 8;
        float acc[8] = {};
        #pragma unroll
        for (int c = 0; c < 32; ++c) {
            float pv = ps[r][c];
            float4 v0 = *(const float4*)&vs[c][d0];
            float4 v1 = *(const float4*)&vs[c][d0 + 4];
            acc[0] = fmaf(pv, v0.x, acc[0]);
            acc[1] = fmaf(pv, v0.y, acc[1]);
            acc[2] = fmaf(pv, v0.z, acc[2]);
            acc[3] = fmaf(pv, v0.w, acc[3]);
            acc[4] = fmaf(pv, v1.x, acc[4]);
            acc[5] = fmaf(pv, v1.y, acc[5]);
            acc[6] = fmaf(pv, v1.z, acc[6]);
            acc[7] = fmaf(pv, v1.w, acc[7]);
        }
        us8 ov;
        #pragma unroll
        for (int j = 0; j < 8; ++j) ov[j] = f2bfu(acc[j]);
        *(us8*)(o + (long)b * SEQ * DIM + (long)r * DIM + hh * HDIM + d0) = ov;
    }
}

// ---------------- x_comb -> bf16
__global__ void comb_kernel(const float* __restrict__ h, bf16_t* __restrict__ xc) {
    int i = blockIdx.x * 256 + threadIdx.x;
    int b = i >> 11;
    int c = i & 2047;
    xc[i] = (bf16_t)h[(long)b * (SEQ * DIM) + c];
}

// ---------------- head layer 3: one wave per (n, b), dot-512
__global__ __launch_bounds__(256) void head3_kernel(const bf16_t* __restrict__ h2,
                                                    const float* __restrict__ w3,
                                                    const float* __restrict__ b3,
                                                    float* __restrict__ out) {
    int gid  = blockIdx.x * 256 + threadIdx.x;
    int wave = gid >> 6;
    int lane = gid & 63;
    if (wave >= NHEAD_OUT * BATCH) return;
    int n = wave >> 6;
    int b = wave & 63;
    const bf16_t* a = h2 + ((long)n * BATCH + b) * IDH;
    const float*  w = w3 + (long)n * IDH;
    float acc = 0.f;
    #pragma unroll
    for (int i = lane; i < IDH; i += 64) acc = fmaf((float)a[i], w[i], acc);
    #pragma unroll
    for (int off = 32; off > 0; off >>= 1) acc += __shfl_down(acc, off);
    if (lane == 0) out[b * NHEAD_OUT + n] = acc + b3[n];
}

extern "C" void kernel_launch(void* const* d_in, const int* in_sizes, int n_in,
                              void* d_out, int out_size, void* d_ws, size_t ws_size,
                              hipStream_t stream) {
    const float* x      = (const float*)d_in[0];
    const float* qkv_w  = (const float*)d_in[1];
    const float* out_w  = (const float*)d_in[2];
    const float* out_b  = (const float*)d_in[3];
    const float* attn_g = (const float*)d_in[4];
    const float* attn_b = (const float*)d_in[5];
    const float* ff_g   = (const float*)d_in[6];
    const float* ff_b   = (const float*)d_in[7];
    const float* ff_w1  = (const float*)d_in[8];
    const float* ff_b1  = (const float*)d_in[9];
    const float* ff_w2  = (const float*)d_in[10];
    const float* ff_b2  = (const float*)d_in[11];
    const float* hw1    = (const float*)d_in[12];
    const float* hb1    = (const float*)d_in[13];
    const float* hw2    = (const float*)d_in[14];
    const float* hb2    = (const float*)d_in[15];
    const float* hw3    = (const float*)d_in[16];
    const float* hb3    = (const float*)d_in[17];
    float* out = (float*)d_out;

    char* p = (char*)d_ws;
    float*  h     = (float*)p;            p += (long)TOK * DIM * 4;
    bf16_t* qkvb  = (bf16_t*)p;           p += (long)TOK * 3 * DIM * 2;
    bf16_t* y     = (bf16_t*)p;           p += (long)TOK * DIM * 2;
    bf16_t* ob    = (bf16_t*)p;           p += (long)TOK * DIM * 2;
    bf16_t* ffb   = (bf16_t*)p;           p += (long)TOK * FFD * 2;
    bf16_t* xc    = (bf16_t*)p;           p += (long)BATCH * 2 * DIM * 2;
    bf16_t* h1    = (bf16_t*)p;           p += (long)NHEAD_OUT * BATCH * IDH * 2;
    bf16_t* h2    = (bf16_t*)p;           p += (long)NHEAD_OUT * BATCH * IDH * 2;
    bf16_t* qkvwt = (bf16_t*)p;           p += (long)LAYERS * DIM * 3 * DIM * 2;
    bf16_t* outwt = (bf16_t*)p;           p += (long)LAYERS * DIM * DIM * 2;
    bf16_t* ff1t  = (bf16_t*)p;           p += (long)LAYERS * DIM * FFD * 2;
    bf16_t* ff2t  = (bf16_t*)p;           p += (long)LAYERS * FFD * DIM * 2;

    // ---- transformer weight transpose+convert (fragment-tiled output) ----
    TxPack tp;
    tp.src[0] = qkv_w; tp.dst[0] = qkvwt; tp.K[0] = DIM; tp.N[0] = 3 * DIM;
    tp.src[1] = out_w; tp.dst[1] = outwt; tp.K[1] = DIM; tp.N[1] = DIM;
    tp.src[2] = ff_w1; tp.dst[2] = ff1t;  tp.K[2] = DIM; tp.N[2] = FFD;
    tp.src[3] = ff_w2; tp.dst[3] = ff2t;  tp.K[3] = FFD; tp.N[3] = DIM;
    int nblk = 0;
    for (int i = 0; i < 4; ++i) {
        tp.blk0[i] = nblk;
        nblk += LAYERS * (tp.K[i] >> 6) * (tp.N[i] >> 6);
    }
    tx64<<<nblk, 256, 0, stream>>>(tp);

    hipMemcpyAsync(h, x, (size_t)TOK * DIM * sizeof(float),
                   hipMemcpyDeviceToDevice, stream);

    for (int l = 0; l < LAYERS; ++l) {
        ln_kernel<true><<<TOK, 256, 0, stream>>>(h, attn_g + l * DIM, attn_b + l * DIM, y);
        gemm32<64, 128, 32, 64, 0><<<dim3(3 * DIM / 128, TOK / 64), 256, 0, stream>>>(
            y, qkvwt + (long)l * DIM * 3 * DIM, nullptr, nullptr, qkvb,
            TOK, 3 * DIM, DIM);
        attn_kernel<<<BATCH * NH, 256, 0, stream>>>(qkvb, ob);
        gemm32<64, 64, 32, 32, 1><<<dim3(DIM / 64, TOK / 64), 256, 0, stream>>>(
            ob, outwt + (long)l * DIM * DIM, out_b + l * DIM, h, h,
            TOK, DIM, DIM);
        ln_kernel<false><<<TOK, 256, 0, stream>>>(h, ff_g + l * DIM, ff_b + l * DIM, y);
        gemm32<64, 128, 32, 64, 2><<<dim3(FFD / 128, TOK / 64), 256, 0, stream>>>(
            y, ff1t + (long)l * DIM * FFD, ff_b1 + l * FFD, nullptr, ffb,
            TOK, FFD, DIM);
        gemm32<64, 64, 32, 32, 1><<<dim3(DIM / 64, TOK / 64), 256, 0, stream>>>(
            ffb, ff2t + (long)l * FFD * DIM, ff_b2 + l * DIM, h, h,
            TOK, DIM, FFD);
    }

    comb_kernel<<<(BATCH * 2 * DIM) / 256, 256, 0, stream>>>(h, xc);

    // heads: fp32 weights read natively, no transpose pass
    gemm_hd<<<dim3(IDH / 64, 1, NHEAD_OUT), 256, 0, stream>>>(
        xc, hw1, hb1, h1,
        IDH, 2 * DIM, 0, (long)2 * DIM * IDH, IDH, (long)BATCH * IDH);
    gemm_hd<<<dim3(IDH / 64, 1, NHEAD_OUT), 256, 0, stream>>>(
        h1, hw2, hb2, h2,
        IDH, IDH, (long)BATCH * IDH, (long)IDH * IDH, IDH, (long)BATCH * IDH);
    head3_kernel<<<(NHEAD_OUT * BATCH * 64) / 256, 256, 0, stream>>>(h2, hw3, hb3, out);
}